// Round 2
// baseline (741.455 us; speedup 1.0000x reference)
//
#include <hip/hip_runtime.h>
#include <hip/hip_bf16.h>
#include <cmath>

// ---------------------------------------------------------------------------
// GAT 2-layer forward. Graph: CSR build (deg/scan/fill), then per-layer:
// GEMM -> alpha -> per-dst segment softmax + aggregate (wave per node).
// All fp32; no float atomics anywhere (CSR gather instead).
// NOTE: harness delivers integer inputs as int32 -> edge_index is const int*.
// ---------------------------------------------------------------------------

__device__ __forceinline__ float lrelu02(float v) { return v > 0.f ? v : 0.2f * v; }

// ---- CSR build ------------------------------------------------------------

__global__ __launch_bounds__(256) void k_deg(const int* __restrict__ ei, int E, int N,
                                             int* __restrict__ deg) {
  int i = blockIdx.x * 256 + threadIdx.x;
  if (i >= E + N) return;
  int dst = (i < E) ? ei[E + i] : (i - E);   // row1 = dst; self loops appended
  atomicAdd(&deg[dst], 1);
}

__global__ __launch_bounds__(1024) void k_scan1(const int* __restrict__ deg, int* __restrict__ offs,
                                                int* __restrict__ part, int n) {
  __shared__ int s[1024];
  int tid = threadIdx.x;
  int i = blockIdx.x * 1024 + tid;
  int v = (i < n) ? deg[i] : 0;
  s[tid] = v;
  __syncthreads();
  for (int off = 1; off < 1024; off <<= 1) {
    int t = (tid >= off) ? s[tid - off] : 0;
    __syncthreads();
    s[tid] += t;
    __syncthreads();
  }
  if (i < n) offs[i] = s[tid] - v;          // exclusive within chunk
  if (tid == 1023) part[blockIdx.x] = s[1023];
}

__global__ __launch_bounds__(1024) void k_scan2(int* __restrict__ part, int nchunk,
                                                int* __restrict__ offs, int n) {
  __shared__ int s[1024];
  int tid = threadIdx.x;
  int v = (tid < nchunk) ? part[tid] : 0;
  s[tid] = v;
  __syncthreads();
  for (int off = 1; off < 1024; off <<= 1) {
    int t = (tid >= off) ? s[tid - off] : 0;
    __syncthreads();
    s[tid] += t;
    __syncthreads();
  }
  if (tid < nchunk) part[tid] = s[tid] - v;  // exclusive chunk bases
  if (tid == 1023) offs[n] = s[1023];        // grand total = E + N
}

__global__ __launch_bounds__(256) void k_scan3(int* __restrict__ offs, const int* __restrict__ part,
                                               int n) {
  int i = blockIdx.x * 256 + threadIdx.x;
  if (i < n) offs[i] += part[i >> 10];
}

__global__ __launch_bounds__(256) void k_fill(const int* __restrict__ ei, int E, int N,
                                              const int* __restrict__ offs, int* __restrict__ cursor,
                                              int* __restrict__ csr) {
  int i = blockIdx.x * 256 + threadIdx.x;
  if (i >= E + N) return;
  int src, dst;
  if (i < E) { src = ei[i]; dst = ei[E + i]; }
  else       { src = i - E; dst = src; }
  int pos = atomicAdd(&cursor[dst], 1);
  csr[offs[dst] + pos] = src;
}

// ---- Layer 1 GEMM: h1 = x @ W1  [N,256]@[256,64], fused alpha_s/alpha_d ----
// block: 256 thr, tile 64 rows x 64 cols, micro 4x4, k-chunks of 64.

__global__ __launch_bounds__(256) void k_gemm1(const float* __restrict__ x, const float* __restrict__ W,
                                               const float* __restrict__ av_s, const float* __restrict__ av_d,
                                               float* __restrict__ h1, float* __restrict__ as1,
                                               float* __restrict__ ad1, int N) {
  __shared__ float xs[64][68];   // [k][row], stride 68 floats (16B-aligned rows)
  __shared__ float wl[64][64];   // [k][col]
  int tid = threadIdx.x;
  int row0 = blockIdx.x * 64;
  int rg = tid >> 4, cg = tid & 15;
  float acc[4][4] = {};
  for (int kc = 0; kc < 256; kc += 64) {
    int rr = tid >> 4, kq = tid & 15;
#pragma unroll
    for (int p = 0; p < 4; ++p) {
      int r = rr + p * 16;
      int grow = row0 + r;
      float4 v = make_float4(0.f, 0.f, 0.f, 0.f);
      if (grow < N) v = *(const float4*)&x[(size_t)grow * 256 + kc + kq * 4];
      xs[kq * 4 + 0][r] = v.x; xs[kq * 4 + 1][r] = v.y;
      xs[kq * 4 + 2][r] = v.z; xs[kq * 4 + 3][r] = v.w;
      *(float4*)&wl[r][kq * 4] = *(const float4*)&W[(size_t)(kc + r) * 64 + kq * 4];
    }
    __syncthreads();
#pragma unroll 4
    for (int k = 0; k < 64; ++k) {
      float4 xv = *(const float4*)&xs[k][rg * 4];
      float4 wv = *(const float4*)&wl[k][cg * 4];
      float xa[4] = {xv.x, xv.y, xv.z, xv.w};
      float wa[4] = {wv.x, wv.y, wv.z, wv.w};
#pragma unroll
      for (int i = 0; i < 4; ++i)
#pragma unroll
        for (int j = 0; j < 4; ++j) acc[i][j] += xa[i] * wa[j];
    }
    __syncthreads();
  }
  // epilogue: write h1, reduce alpha over the 8 cols of each head (cg pairs)
  float av[4], bv[4];
#pragma unroll
  for (int j = 0; j < 4; ++j) { av[j] = av_s[cg * 4 + j]; bv[j] = av_d[cg * 4 + j]; }
#pragma unroll
  for (int i = 0; i < 4; ++i) {
    int row = row0 + rg * 4 + i;
    if (row < N) {
      float4 o; o.x = acc[i][0]; o.y = acc[i][1]; o.z = acc[i][2]; o.w = acc[i][3];
      *(float4*)&h1[(size_t)row * 64 + cg * 4] = o;
      float ps = acc[i][0] * av[0] + acc[i][1] * av[1] + acc[i][2] * av[2] + acc[i][3] * av[3];
      float pd = acc[i][0] * bv[0] + acc[i][1] * bv[1] + acc[i][2] * bv[2] + acc[i][3] * bv[3];
      ps += __shfl_xor(ps, 1);
      pd += __shfl_xor(pd, 1);
      if ((cg & 1) == 0) {
        as1[row * 8 + (cg >> 1)] = ps;
        ad1[row * 8 + (cg >> 1)] = pd;
      }
    }
  }
}

// ---- Layer 1 aggregate: segment softmax + sum, bias, ELU. wave/node -------

__global__ __launch_bounds__(256) void k_agg1(const int* __restrict__ csr, const int* __restrict__ offs,
                                              const float* __restrict__ h1, const float* __restrict__ as1,
                                              const float* __restrict__ ad1, const float* __restrict__ b1,
                                              float* __restrict__ helu, int N) {
  int tid = threadIdx.x;
  int node = blockIdx.x * 4 + (tid >> 6);
  if (node >= N) return;
  int lane = tid & 63;
  int h = lane >> 3, cl = lane & 7;
  int beg = offs[node], end = offs[node + 1];
  float adv = ad1[node * 8 + h];
  // pass 1: per-head max, edges split across the 8 lanes of the head
  float m = -1e30f;
  for (int e = beg + cl; e < end; e += 8) {
    int s = csr[e];
    float v = lrelu02(as1[s * 8 + h] + adv);
    m = fmaxf(m, v);
  }
  m = fmaxf(m, __shfl_xor(m, 1));
  m = fmaxf(m, __shfl_xor(m, 2));
  m = fmaxf(m, __shfl_xor(m, 4));
  // pass 2: exp, denom, weighted gather of h1[src]
  float denom = 0.f, acc = 0.f;
  for (int e = beg; e < end; ++e) {
    int s = csr[e];
    float v = lrelu02(as1[s * 8 + h] + adv);
    float w = __expf(v - m);
    denom += w;
    acc += w * h1[(size_t)s * 64 + lane];
  }
  float o = acc / denom + b1[lane];
  o = o > 0.f ? o : expm1f(o);   // ELU(alpha=1)
  helu[(size_t)node * 64 + lane] = o;
}

// ---- Layer 2 GEMM: h2 = helu @ W2  [N,64]@[64,100] ------------------------
// block: 256 thr, tile 40 rows x 100 cols, micro 4x4 (rg<10, cg<25).

__global__ __launch_bounds__(256) void k_gemm2(const float* __restrict__ he, const float* __restrict__ W2,
                                               float* __restrict__ h2, int N) {
  __shared__ float het[64][44];     // [k][row]
  __shared__ float w2l[64 * 100];   // [k][col]
  int tid = threadIdx.x;
  int row0 = blockIdx.x * 40;
  for (int i = tid; i < 6400; i += 256) w2l[i] = W2[i];
  for (int idx = tid; idx < 640; idx += 256) {
    int r = idx >> 4, kq = idx & 15;
    int grow = row0 + r;
    float4 v = make_float4(0.f, 0.f, 0.f, 0.f);
    if (grow < N) v = *(const float4*)&he[(size_t)grow * 64 + kq * 4];
    het[kq * 4 + 0][r] = v.x; het[kq * 4 + 1][r] = v.y;
    het[kq * 4 + 2][r] = v.z; het[kq * 4 + 3][r] = v.w;
  }
  __syncthreads();
  int rg = tid / 25, cg = tid % 25;
  if (rg >= 10) return;
  float acc[4][4] = {};
#pragma unroll 4
  for (int k = 0; k < 64; ++k) {
    float4 xv = *(const float4*)&het[k][rg * 4];
    float4 wv = *(const float4*)&w2l[k * 100 + cg * 4];
    float xa[4] = {xv.x, xv.y, xv.z, xv.w};
    float wa[4] = {wv.x, wv.y, wv.z, wv.w};
#pragma unroll
    for (int i = 0; i < 4; ++i)
#pragma unroll
      for (int j = 0; j < 4; ++j) acc[i][j] += xa[i] * wa[j];
  }
#pragma unroll
  for (int i = 0; i < 4; ++i) {
    int row = row0 + rg * 4 + i;
    if (row < N) {
      float4 o; o.x = acc[i][0]; o.y = acc[i][1]; o.z = acc[i][2]; o.w = acc[i][3];
      *(float4*)&h2[(size_t)row * 100 + cg * 4] = o;
    }
  }
}

// ---- Layer 2 alpha: as2/ad2 = h2 . a2  (wave per node) --------------------

__global__ __launch_bounds__(256) void k_alpha2(const float* __restrict__ h2, const float* __restrict__ a2s,
                                                const float* __restrict__ a2d, float* __restrict__ as2,
                                                float* __restrict__ ad2, int N) {
  int tid = threadIdx.x;
  int node = blockIdx.x * 4 + (tid >> 6);
  if (node >= N) return;
  int lane = tid & 63;
  float v = h2[(size_t)node * 100 + lane];
  float s = v * a2s[lane];
  float d = v * a2d[lane];
  if (lane < 36) {
    float v2 = h2[(size_t)node * 100 + 64 + lane];
    s += v2 * a2s[64 + lane];
    d += v2 * a2d[64 + lane];
  }
#pragma unroll
  for (int off = 32; off; off >>= 1) { s += __shfl_xor(s, off); d += __shfl_xor(d, off); }
  if (lane == 0) { as2[node] = s; ad2[node] = d; }
}

// ---- Layer 2 aggregate + bias + sigmoid (wave per node, 100 channels) -----

__global__ __launch_bounds__(256) void k_agg2(const int* __restrict__ csr, const int* __restrict__ offs,
                                              const float* __restrict__ h2, const float* __restrict__ as2,
                                              const float* __restrict__ ad2, const float* __restrict__ b2,
                                              float* __restrict__ out, int N) {
  int tid = threadIdx.x;
  int node = blockIdx.x * 4 + (tid >> 6);
  if (node >= N) return;
  int lane = tid & 63;
  int beg = offs[node], end = offs[node + 1];
  float adv = ad2[node];
  // pass 1: max over edges, split across 64 lanes
  float m = -1e30f;
  for (int e = beg + lane; e < end; e += 64) {
    int s = csr[e];
    m = fmaxf(m, lrelu02(as2[s] + adv));
  }
#pragma unroll
  for (int off = 32; off; off >>= 1) m = fmaxf(m, __shfl_xor(m, off));
  // pass 2
  float denom = 0.f, acc0 = 0.f, acc1 = 0.f;
  bool two = lane < 36;
  for (int e = beg; e < end; ++e) {
    int s = csr[e];
    float w = __expf(lrelu02(as2[s] + adv) - m);
    denom += w;
    acc0 += w * h2[(size_t)s * 100 + lane];
    if (two) acc1 += w * h2[(size_t)s * 100 + 64 + lane];
  }
  float r = 1.f / denom;
  out[(size_t)node * 100 + lane] = 1.f / (1.f + __expf(-(acc0 * r + b2[lane])));
  if (two)
    out[(size_t)node * 100 + 64 + lane] = 1.f / (1.f + __expf(-(acc1 * r + b2[64 + lane])));
}

// ---------------------------------------------------------------------------

extern "C" void kernel_launch(void* const* d_in, const int* in_sizes, int n_in,
                              void* d_out, int out_size, void* d_ws, size_t ws_size,
                              hipStream_t stream) {
  const float* x    = (const float*)d_in[0];
  const int*   ei   = (const int*)d_in[1];    // harness converts integer inputs to int32
  const float* W1   = (const float*)d_in[2];
  const float* a_s1 = (const float*)d_in[3];
  const float* a_d1 = (const float*)d_in[4];
  const float* b1   = (const float*)d_in[5];
  const float* W2   = (const float*)d_in[6];
  const float* a_s2 = (const float*)d_in[7];
  const float* a_d2 = (const float*)d_in[8];
  const float* b2   = (const float*)d_in[9];
  float* out = (float*)d_out;

  const int N = in_sizes[0] / 256;
  const int E = in_sizes[1] / 2;
  const int EP = E + N;

  // workspace layout (256B-aligned slices). h1 and h2 share one 40MB slot:
  // h1 ([N,64]) is dead before k_gemm2 writes h2 ([N,100]).
  char* w = (char*)d_ws;
  size_t off = 0;
  auto alloc = [&](size_t bytes) -> char* {
    char* p = w + off;
    off = (off + bytes + 255) & ~(size_t)255;
    return p;
  };
  float* h12  = (float*)alloc((size_t)N * 100 * 4);  // h1 uses first N*64, h2 uses N*100
  float* h1   = h12;
  float* h2   = h12;
  float* helu = (float*)alloc((size_t)N * 64 * 4);
  float* as1  = (float*)alloc((size_t)N * 8 * 4);
  float* ad1  = (float*)alloc((size_t)N * 8 * 4);
  float* as2  = (float*)alloc((size_t)N * 4);
  float* ad2  = (float*)alloc((size_t)N * 4);
  int*   deg    = (int*)alloc((size_t)N * 4);
  int*   cursor = (int*)alloc((size_t)N * 4);
  int*   offs   = (int*)alloc((size_t)(N + 1) * 4);
  int*   csr    = (int*)alloc((size_t)EP * 4);
  int*   part   = (int*)alloc(1024 * 4);
  (void)ws_size; (void)n_in; (void)out_size;

  hipMemsetAsync(deg, 0, (size_t)N * 4, stream);
  hipMemsetAsync(cursor, 0, (size_t)N * 4, stream);

  k_deg<<<(EP + 255) / 256, 256, 0, stream>>>(ei, E, N, deg);
  int nchunk = (N + 1023) / 1024;
  k_scan1<<<nchunk, 1024, 0, stream>>>(deg, offs, part, N);
  k_scan2<<<1, 1024, 0, stream>>>(part, nchunk, offs, N);
  k_scan3<<<(N + 255) / 256, 256, 0, stream>>>(offs, part, N);
  k_fill<<<(EP + 255) / 256, 256, 0, stream>>>(ei, E, N, offs, cursor, csr);

  k_gemm1<<<(N + 63) / 64, 256, 0, stream>>>(x, W1, a_s1, a_d1, h1, as1, ad1, N);
  k_agg1<<<(N + 3) / 4, 256, 0, stream>>>(csr, offs, h1, as1, ad1, b1, helu, N);

  k_gemm2<<<(N + 39) / 40, 256, 0, stream>>>(helu, W2, h2, N);
  k_alpha2<<<(N + 3) / 4, 256, 0, stream>>>(h2, a_s2, a_d2, as2, ad2, N);
  k_agg2<<<(N + 3) / 4, 256, 0, stream>>>(csr, offs, h2, as2, ad2, b2, out, N);
}

// Round 3
// 481.208 us; speedup vs baseline: 1.5408x; 1.5408x over previous
//
#include <hip/hip_runtime.h>
#include <hip/hip_bf16.h>
#include <cmath>

// ---------------------------------------------------------------------------
// GAT 2-layer forward. CSR build (deg/scan/fill), then per-layer:
// GEMM -> alpha -> chunked online-softmax aggregate (wave per node, 64-edge
// chunks, lane-parallel alpha gather + x4-unrolled row gather).
// All fp32; no float atomics. edge_index arrives as int32 from the harness.
// ---------------------------------------------------------------------------

__device__ __forceinline__ float lrelu02(float v) { return v > 0.f ? v : 0.2f * v; }

// ---- CSR build ------------------------------------------------------------

__global__ __launch_bounds__(256) void k_deg(const int* __restrict__ ei, int E, int N,
                                             int* __restrict__ deg) {
  int i = blockIdx.x * 256 + threadIdx.x;
  if (i >= E + N) return;
  int dst = (i < E) ? ei[E + i] : (i - E);   // row1 = dst; self loops appended
  atomicAdd(&deg[dst], 1);
}

__global__ __launch_bounds__(1024) void k_scan1(const int* __restrict__ deg, int* __restrict__ offs,
                                                int* __restrict__ part, int n) {
  __shared__ int s[1024];
  int tid = threadIdx.x;
  int i = blockIdx.x * 1024 + tid;
  int v = (i < n) ? deg[i] : 0;
  s[tid] = v;
  __syncthreads();
  for (int off = 1; off < 1024; off <<= 1) {
    int t = (tid >= off) ? s[tid - off] : 0;
    __syncthreads();
    s[tid] += t;
    __syncthreads();
  }
  if (i < n) offs[i] = s[tid] - v;          // exclusive within chunk
  if (tid == 1023) part[blockIdx.x] = s[1023];
}

__global__ __launch_bounds__(1024) void k_scan2(int* __restrict__ part, int nchunk,
                                                int* __restrict__ offs, int n) {
  __shared__ int s[1024];
  int tid = threadIdx.x;
  int v = (tid < nchunk) ? part[tid] : 0;
  s[tid] = v;
  __syncthreads();
  for (int off = 1; off < 1024; off <<= 1) {
    int t = (tid >= off) ? s[tid - off] : 0;
    __syncthreads();
    s[tid] += t;
    __syncthreads();
  }
  if (tid < nchunk) part[tid] = s[tid] - v;  // exclusive chunk bases
  if (tid == 1023) offs[n] = s[1023];        // grand total = E + N
}

__global__ __launch_bounds__(256) void k_scan3(int* __restrict__ offs, const int* __restrict__ part,
                                               int n) {
  int i = blockIdx.x * 256 + threadIdx.x;
  if (i < n) offs[i] += part[i >> 10];
}

__global__ __launch_bounds__(256) void k_fill(const int* __restrict__ ei, int E, int N,
                                              const int* __restrict__ offs, int* __restrict__ cursor,
                                              int* __restrict__ csr) {
  int i = blockIdx.x * 256 + threadIdx.x;
  if (i >= E + N) return;
  int src, dst;
  if (i < E) { src = ei[i]; dst = ei[E + i]; }
  else       { src = i - E; dst = src; }
  int pos = atomicAdd(&cursor[dst], 1);
  csr[offs[dst] + pos] = src;
}

// ---- Layer 1 GEMM: h1 = x @ W1  [N,256]@[256,64], fused alpha_s/alpha_d ----

__global__ __launch_bounds__(256) void k_gemm1(const float* __restrict__ x, const float* __restrict__ W,
                                               const float* __restrict__ av_s, const float* __restrict__ av_d,
                                               float* __restrict__ h1, float* __restrict__ as1,
                                               float* __restrict__ ad1, int N) {
  __shared__ float xs[64][68];   // [k][row]
  __shared__ float wl[64][64];   // [k][col]
  int tid = threadIdx.x;
  int row0 = blockIdx.x * 64;
  int rg = tid >> 4, cg = tid & 15;
  float acc[4][4] = {};
  for (int kc = 0; kc < 256; kc += 64) {
    int rr = tid >> 4, kq = tid & 15;
#pragma unroll
    for (int p = 0; p < 4; ++p) {
      int r = rr + p * 16;
      int grow = row0 + r;
      float4 v = make_float4(0.f, 0.f, 0.f, 0.f);
      if (grow < N) v = *(const float4*)&x[(size_t)grow * 256 + kc + kq * 4];
      xs[kq * 4 + 0][r] = v.x; xs[kq * 4 + 1][r] = v.y;
      xs[kq * 4 + 2][r] = v.z; xs[kq * 4 + 3][r] = v.w;
      *(float4*)&wl[r][kq * 4] = *(const float4*)&W[(size_t)(kc + r) * 64 + kq * 4];
    }
    __syncthreads();
#pragma unroll 4
    for (int k = 0; k < 64; ++k) {
      float4 xv = *(const float4*)&xs[k][rg * 4];
      float4 wv = *(const float4*)&wl[k][cg * 4];
      float xa[4] = {xv.x, xv.y, xv.z, xv.w};
      float wa[4] = {wv.x, wv.y, wv.z, wv.w};
#pragma unroll
      for (int i = 0; i < 4; ++i)
#pragma unroll
        for (int j = 0; j < 4; ++j) acc[i][j] += xa[i] * wa[j];
    }
    __syncthreads();
  }
  float av[4], bv[4];
#pragma unroll
  for (int j = 0; j < 4; ++j) { av[j] = av_s[cg * 4 + j]; bv[j] = av_d[cg * 4 + j]; }
#pragma unroll
  for (int i = 0; i < 4; ++i) {
    int row = row0 + rg * 4 + i;
    if (row < N) {
      float4 o; o.x = acc[i][0]; o.y = acc[i][1]; o.z = acc[i][2]; o.w = acc[i][3];
      *(float4*)&h1[(size_t)row * 64 + cg * 4] = o;
      float ps = acc[i][0] * av[0] + acc[i][1] * av[1] + acc[i][2] * av[2] + acc[i][3] * av[3];
      float pd = acc[i][0] * bv[0] + acc[i][1] * bv[1] + acc[i][2] * bv[2] + acc[i][3] * bv[3];
      ps += __shfl_xor(ps, 1);
      pd += __shfl_xor(pd, 1);
      if ((cg & 1) == 0) {
        as1[row * 8 + (cg >> 1)] = ps;
        ad1[row * 8 + (cg >> 1)] = pd;
      }
    }
  }
}

// ---- Layer 1 aggregate: chunked online softmax, 8 heads x 8 lanes ---------
// wave per node; 64-edge chunks; w cached in LDS (padded 66 vs 8-way bank
// conflict); gather loop unrolled x4 for memory-level parallelism.

__global__ __launch_bounds__(256) void k_agg1(const int* __restrict__ csr, const int* __restrict__ offs,
                                              const float* __restrict__ h1, const float* __restrict__ as1,
                                              const float* __restrict__ ad1, const float* __restrict__ b1,
                                              float* __restrict__ helu, int N) {
  __shared__ float wsm[4][8][66];
  __shared__ int   scs[4][64];
  int tid = threadIdx.x;
  int slot = tid >> 6;
  int node = blockIdx.x * 4 + slot;
  if (node >= N) return;
  int lane = tid & 63;
  int h = lane >> 3, cl = lane & 7;
  int beg = offs[node], end = offs[node + 1];
  int deg = end - beg;
  float adv = ad1[node * 8 + h];
  float m = -1e30f, denom = 0.f, acc = 0.f;
  for (int c0 = 0; c0 < deg; c0 += 64) {
    int cn = min(64, deg - c0);
    if (lane < cn) scs[slot][lane] = csr[beg + c0 + lane];
    // phase A: per-head alpha gather (lane-parallel), chunk max
    float cmax = -1e30f;
    for (int i = cl; i < cn; i += 8) {
      int s = scs[slot][i];
      float v = lrelu02(as1[s * 8 + h] + adv);
      wsm[slot][h][i] = v;
      cmax = fmaxf(cmax, v);
    }
    cmax = fmaxf(cmax, __shfl_xor(cmax, 1));
    cmax = fmaxf(cmax, __shfl_xor(cmax, 2));
    cmax = fmaxf(cmax, __shfl_xor(cmax, 4));
    float mnew = fmaxf(m, cmax);
    float sc = __expf(m - mnew);
    denom *= sc; acc *= sc; m = mnew;
    // phase B: exponentiate in LDS, partial denom
    float dp = 0.f;
    for (int i = cl; i < cn; i += 8) {
      float wv = __expf(wsm[slot][h][i] - m);
      wsm[slot][h][i] = wv;
      dp += wv;
    }
    dp += __shfl_xor(dp, 1);
    dp += __shfl_xor(dp, 2);
    dp += __shfl_xor(dp, 4);
    denom += dp;
    // phase C: weighted row gather, unrolled x4
    int i = 0;
    for (; i + 4 <= cn; i += 4) {
      float w0 = wsm[slot][h][i + 0], w1 = wsm[slot][h][i + 1];
      float w2 = wsm[slot][h][i + 2], w3 = wsm[slot][h][i + 3];
      int s0 = scs[slot][i + 0], s1 = scs[slot][i + 1];
      int s2 = scs[slot][i + 2], s3 = scs[slot][i + 3];
      acc += w0 * h1[(size_t)s0 * 64 + lane];
      acc += w1 * h1[(size_t)s1 * 64 + lane];
      acc += w2 * h1[(size_t)s2 * 64 + lane];
      acc += w3 * h1[(size_t)s3 * 64 + lane];
    }
    for (; i < cn; ++i) {
      float wv = wsm[slot][h][i];
      int s = scs[slot][i];
      acc += wv * h1[(size_t)s * 64 + lane];
    }
  }
  float o = acc / denom + b1[lane];
  o = o > 0.f ? o : expm1f(o);   // ELU(alpha=1)
  helu[(size_t)node * 64 + lane] = o;
}

// ---- Layer 2 GEMM: h2 = helu @ W2  [N,64]@[64,100] ------------------------

__global__ __launch_bounds__(256) void k_gemm2(const float* __restrict__ he, const float* __restrict__ W2,
                                               float* __restrict__ h2, int N) {
  __shared__ float het[64][44];     // [k][row]
  __shared__ float w2l[64 * 100];   // [k][col]
  int tid = threadIdx.x;
  int row0 = blockIdx.x * 40;
  for (int i = tid; i < 6400; i += 256) w2l[i] = W2[i];
  for (int idx = tid; idx < 640; idx += 256) {
    int r = idx >> 4, kq = idx & 15;
    int grow = row0 + r;
    float4 v = make_float4(0.f, 0.f, 0.f, 0.f);
    if (grow < N) v = *(const float4*)&he[(size_t)grow * 64 + kq * 4];
    het[kq * 4 + 0][r] = v.x; het[kq * 4 + 1][r] = v.y;
    het[kq * 4 + 2][r] = v.z; het[kq * 4 + 3][r] = v.w;
  }
  __syncthreads();
  int rg = tid / 25, cg = tid % 25;
  if (rg >= 10) return;
  float acc[4][4] = {};
#pragma unroll 4
  for (int k = 0; k < 64; ++k) {
    float4 xv = *(const float4*)&het[k][rg * 4];
    float4 wv = *(const float4*)&w2l[k * 100 + cg * 4];
    float xa[4] = {xv.x, xv.y, xv.z, xv.w};
    float wa[4] = {wv.x, wv.y, wv.z, wv.w};
#pragma unroll
    for (int i = 0; i < 4; ++i)
#pragma unroll
      for (int j = 0; j < 4; ++j) acc[i][j] += xa[i] * wa[j];
  }
#pragma unroll
  for (int i = 0; i < 4; ++i) {
    int row = row0 + rg * 4 + i;
    if (row < N) {
      float4 o; o.x = acc[i][0]; o.y = acc[i][1]; o.z = acc[i][2]; o.w = acc[i][3];
      *(float4*)&h2[(size_t)row * 100 + cg * 4] = o;
    }
  }
}

// ---- Layer 2 alpha --------------------------------------------------------

__global__ __launch_bounds__(256) void k_alpha2(const float* __restrict__ h2, const float* __restrict__ a2s,
                                                const float* __restrict__ a2d, float* __restrict__ as2,
                                                float* __restrict__ ad2, int N) {
  int tid = threadIdx.x;
  int node = blockIdx.x * 4 + (tid >> 6);
  if (node >= N) return;
  int lane = tid & 63;
  float v = h2[(size_t)node * 100 + lane];
  float s = v * a2s[lane];
  float d = v * a2d[lane];
  if (lane < 36) {
    float v2 = h2[(size_t)node * 100 + 64 + lane];
    s += v2 * a2s[64 + lane];
    d += v2 * a2d[64 + lane];
  }
#pragma unroll
  for (int off = 32; off; off >>= 1) { s += __shfl_xor(s, off); d += __shfl_xor(d, off); }
  if (lane == 0) { as2[node] = s; ad2[node] = d; }
}

// ---- Layer 2 aggregate: chunked online softmax + sigmoid ------------------
// wave per node; chunk alpha gather is 64-lane-parallel; (w,src) pairs in
// LDS float2 (one ds_read_b64 broadcast per edge); gather unrolled x4.

__global__ __launch_bounds__(256) void k_agg2(const int* __restrict__ csr, const int* __restrict__ offs,
                                              const float* __restrict__ h2, const float* __restrict__ as2,
                                              const float* __restrict__ ad2, const float* __restrict__ b2,
                                              float* __restrict__ out, int N) {
  __shared__ float2 lds2[4][64];
  int tid = threadIdx.x;
  int slot = tid >> 6;
  int node = blockIdx.x * 4 + slot;
  if (node >= N) return;
  int lane = tid & 63;
  int beg = offs[node], end = offs[node + 1];
  int deg = end - beg;
  float adv = ad2[node];
  bool two = lane < 36;
  float m = -1e30f, denom = 0.f, acc0 = 0.f, acc1 = 0.f;
  for (int c0 = 0; c0 < deg; c0 += 64) {
    int cn = min(64, deg - c0);
    int sreg = 0; float v = -1e30f;
    if (lane < cn) {
      sreg = csr[beg + c0 + lane];
      v = lrelu02(as2[sreg] + adv);
    }
    float cm = v;
#pragma unroll
    for (int off = 32; off; off >>= 1) cm = fmaxf(cm, __shfl_xor(cm, off));
    float mnew = fmaxf(m, cm);
    float sc = __expf(m - mnew);
    denom *= sc; acc0 *= sc; acc1 *= sc; m = mnew;
    float w = (lane < cn) ? __expf(v - m) : 0.f;
    lds2[slot][lane] = make_float2(w, __int_as_float(sreg));
    float dp = w;
#pragma unroll
    for (int off = 32; off; off >>= 1) dp += __shfl_xor(dp, off);
    denom += dp;
    int i = 0;
    for (; i + 4 <= cn; i += 4) {
      float2 e0 = lds2[slot][i + 0];
      float2 e1 = lds2[slot][i + 1];
      float2 e2 = lds2[slot][i + 2];
      float2 e3 = lds2[slot][i + 3];
      const float* r0 = h2 + (size_t)__float_as_int(e0.y) * 100;
      const float* r1 = h2 + (size_t)__float_as_int(e1.y) * 100;
      const float* r2 = h2 + (size_t)__float_as_int(e2.y) * 100;
      const float* r3 = h2 + (size_t)__float_as_int(e3.y) * 100;
      acc0 += e0.x * r0[lane];
      acc0 += e1.x * r1[lane];
      acc0 += e2.x * r2[lane];
      acc0 += e3.x * r3[lane];
      if (two) {
        acc1 += e0.x * r0[64 + lane];
        acc1 += e1.x * r1[64 + lane];
        acc1 += e2.x * r2[64 + lane];
        acc1 += e3.x * r3[64 + lane];
      }
    }
    for (; i < cn; ++i) {
      float2 e0 = lds2[slot][i];
      const float* r0 = h2 + (size_t)__float_as_int(e0.y) * 100;
      acc0 += e0.x * r0[lane];
      if (two) acc1 += e0.x * r0[64 + lane];
    }
  }
  float r = 1.f / denom;
  out[(size_t)node * 100 + lane] = 1.f / (1.f + __expf(-(acc0 * r + b2[lane])));
  if (two)
    out[(size_t)node * 100 + 64 + lane] = 1.f / (1.f + __expf(-(acc1 * r + b2[64 + lane])));
}

// ---------------------------------------------------------------------------

extern "C" void kernel_launch(void* const* d_in, const int* in_sizes, int n_in,
                              void* d_out, int out_size, void* d_ws, size_t ws_size,
                              hipStream_t stream) {
  const float* x    = (const float*)d_in[0];
  const int*   ei   = (const int*)d_in[1];    // harness converts integer inputs to int32
  const float* W1   = (const float*)d_in[2];
  const float* a_s1 = (const float*)d_in[3];
  const float* a_d1 = (const float*)d_in[4];
  const float* b1   = (const float*)d_in[5];
  const float* W2   = (const float*)d_in[6];
  const float* a_s2 = (const float*)d_in[7];
  const float* a_d2 = (const float*)d_in[8];
  const float* b2   = (const float*)d_in[9];
  float* out = (float*)d_out;

  const int N = in_sizes[0] / 256;
  const int E = in_sizes[1] / 2;
  const int EP = E + N;

  char* w = (char*)d_ws;
  size_t off = 0;
  auto alloc = [&](size_t bytes) -> char* {
    char* p = w + off;
    off = (off + bytes + 255) & ~(size_t)255;
    return p;
  };
  float* h12  = (float*)alloc((size_t)N * 100 * 4);  // h1 uses N*64, h2 uses N*100
  float* h1   = h12;
  float* h2   = h12;
  float* helu = (float*)alloc((size_t)N * 64 * 4);
  float* as1  = (float*)alloc((size_t)N * 8 * 4);
  float* ad1  = (float*)alloc((size_t)N * 8 * 4);
  float* as2  = (float*)alloc((size_t)N * 4);
  float* ad2  = (float*)alloc((size_t)N * 4);
  int*   deg    = (int*)alloc((size_t)N * 4);
  int*   cursor = (int*)alloc((size_t)N * 4);
  int*   offs   = (int*)alloc((size_t)(N + 1) * 4);
  int*   csr    = (int*)alloc((size_t)EP * 4);
  int*   part   = (int*)alloc(1024 * 4);
  (void)ws_size; (void)n_in; (void)out_size;

  hipMemsetAsync(deg, 0, (size_t)N * 4, stream);
  hipMemsetAsync(cursor, 0, (size_t)N * 4, stream);

  k_deg<<<(EP + 255) / 256, 256, 0, stream>>>(ei, E, N, deg);
  int nchunk = (N + 1023) / 1024;
  k_scan1<<<nchunk, 1024, 0, stream>>>(deg, offs, part, N);
  k_scan2<<<1, 1024, 0, stream>>>(part, nchunk, offs, N);
  k_scan3<<<(N + 255) / 256, 256, 0, stream>>>(offs, part, N);
  k_fill<<<(EP + 255) / 256, 256, 0, stream>>>(ei, E, N, offs, cursor, csr);

  k_gemm1<<<(N + 63) / 64, 256, 0, stream>>>(x, W1, a_s1, a_d1, h1, as1, ad1, N);
  k_agg1<<<(N + 3) / 4, 256, 0, stream>>>(csr, offs, h1, as1, ad1, b1, helu, N);

  k_gemm2<<<(N + 39) / 40, 256, 0, stream>>>(helu, W2, h2, N);
  k_alpha2<<<(N + 3) / 4, 256, 0, stream>>>(h2, a_s2, a_d2, as2, ad2, N);
  k_agg2<<<(N + 3) / 4, 256, 0, stream>>>(csr, offs, h2, as2, ad2, b2, out, N);
}

// Round 4
// 379.249 us; speedup vs baseline: 1.9551x; 1.2688x over previous
//
#include <hip/hip_runtime.h>
#include <hip/hip_bf16.h>
#include <cmath>

// ---------------------------------------------------------------------------
// GAT 2-layer forward.
// CSR build via 2-level bucketing (bucket = dst>>9): hist -> scan -> bin ->
// per-bucket LDS fill (scatter confined to one XCD's L2 -> no 16x write amp).
// Then per layer: GEMM -> alpha -> chunked online-softmax aggregate.
// All fp32; edge_index arrives as int32 from the harness.
// ---------------------------------------------------------------------------

#define BSH 9                 // 512 nodes per bucket; requires N <= 131072
#define BNN (1 << BSH)

__device__ __forceinline__ float lrelu02(float v) { return v > 0.f ? v : 0.2f * v; }

// ---- CSR build: pass A1 — bucket histogram --------------------------------

__global__ __launch_bounds__(256) void k_hist(const int* __restrict__ ei, int E,
                                              int* __restrict__ bhist) {
  __shared__ int lh[256];
  int tid = threadIdx.x;
  lh[tid] = 0;
  __syncthreads();
  int base = blockIdx.x * 2048;
#pragma unroll
  for (int j = 0; j < 8; ++j) {
    int e = base + j * 256 + tid;
    if (e < E) atomicAdd(&lh[ei[E + e] >> BSH], 1);
  }
  __syncthreads();
  if (lh[tid]) atomicAdd(&bhist[tid], lh[tid]);
}

// ---- pass A2 — scan bucket counts (single block) --------------------------

__global__ __launch_bounds__(256) void k_bscan(const int* __restrict__ bhist,
                                               int* __restrict__ bbase, int* __restrict__ bcur,
                                               int* __restrict__ offs, int K, int E, int N) {
  __shared__ int s[256];
  int tid = threadIdx.x;
  int v = (tid < K) ? bhist[tid] : 0;
  s[tid] = v;
  __syncthreads();
  for (int off = 1; off < 256; off <<= 1) {
    int t = (tid >= off) ? s[tid - off] : 0;
    __syncthreads();
    s[tid] += t;
    __syncthreads();
  }
  int excl = s[tid] - v;
  if (tid < K) { bbase[tid] = excl; bcur[tid] = excl; }
  if (tid == 255) bbase[K] = s[255];    // = E
  if (tid == 0) offs[N] = E + N;
}

// ---- pass A3 — bin edges into buckets as (src, dst_local) -----------------

__global__ __launch_bounds__(256) void k_bin(const int* __restrict__ ei, int E,
                                             int* __restrict__ bcur, int2* __restrict__ binned) {
  __shared__ int lh[256];
  __shared__ int lbase[256];
  int tid = threadIdx.x;
  lh[tid] = 0;
  __syncthreads();
  int base = blockIdx.x * 2048;
  int bj[8], rk[8], sj[8], dl[8];
#pragma unroll
  for (int j = 0; j < 8; ++j) {
    int e = base + j * 256 + tid;
    bj[j] = -1;
    if (e < E) {
      sj[j] = ei[e];
      int d = ei[E + e];
      bj[j] = d >> BSH;
      dl[j] = d & (BNN - 1);
      rk[j] = atomicAdd(&lh[bj[j]], 1);
    }
  }
  __syncthreads();
  if (lh[tid]) lbase[tid] = atomicAdd(&bcur[tid], lh[tid]);
  __syncthreads();
#pragma unroll
  for (int j = 0; j < 8; ++j)
    if (bj[j] >= 0) binned[lbase[bj[j]] + rk[j]] = make_int2(sj[j], dl[j]);
}

// ---- pass B — per-bucket CSR fill (one block per bucket) ------------------
// Local hist+scan in LDS, offs written coalesced; csr scatter stays inside
// this bucket's ~36KB segment (one XCD's L2) so lines are written back once.

__global__ __launch_bounds__(256) void k_bucket(const int2* __restrict__ binned,
                                                const int* __restrict__ bbase,
                                                int* __restrict__ offs, int* __restrict__ csr,
                                                int N) {
  __shared__ int hist[BNN], loffS[BNN], cur[BNN];
  __shared__ int s[256];
  int tid = threadIdx.x;
  int b = blockIdx.x;
  int node0 = b << BSH;
  int sl = min(BNN, N - node0);
  int e0 = bbase[b], e1 = bbase[b + 1];
  int cbase = e0 + min(node0, N);          // csr base incl. upstream self-loops
  hist[tid] = 0; hist[tid + 256] = 0;
  __syncthreads();
  for (int e = e0 + tid; e < e1; e += 256) atomicAdd(&hist[binned[e].y], 1);
  __syncthreads();
  int a0 = hist[2 * tid], a1 = hist[2 * tid + 1];
  s[tid] = a0 + a1;
  __syncthreads();
  for (int off = 1; off < 256; off <<= 1) {
    int t = (tid >= off) ? s[tid - off] : 0;
    __syncthreads();
    s[tid] += t;
    __syncthreads();
  }
  int excl = s[tid] - (a0 + a1);
  // + i accounts for one self-loop per preceding node in this bucket
  loffS[2 * tid]     = excl + 2 * tid;
  loffS[2 * tid + 1] = excl + a0 + 2 * tid + 1;
  __syncthreads();
  cur[2 * tid] = loffS[2 * tid];
  cur[2 * tid + 1] = loffS[2 * tid + 1];
  if (2 * tid < sl)     offs[node0 + 2 * tid]     = cbase + loffS[2 * tid];
  if (2 * tid + 1 < sl) offs[node0 + 2 * tid + 1] = cbase + loffS[2 * tid + 1];
  __syncthreads();
  for (int e = e0 + tid; e < e1; e += 256) {
    int2 u = binned[e];
    int p = atomicAdd(&cur[u.y], 1);
    csr[cbase + p] = u.x;
  }
  for (int i = tid; i < sl; i += 256) {
    int p = atomicAdd(&cur[i], 1);
    csr[cbase + p] = node0 + i;            // self loop
  }
}

// ---- Layer 1 GEMM: h1 = x @ W1  [N,256]@[256,64], fused alpha_s/alpha_d ----

__global__ __launch_bounds__(256) void k_gemm1(const float* __restrict__ x, const float* __restrict__ W,
                                               const float* __restrict__ av_s, const float* __restrict__ av_d,
                                               float* __restrict__ h1, float* __restrict__ as1,
                                               float* __restrict__ ad1, int N) {
  __shared__ float xs[64][68];   // [k][row]
  __shared__ float wl[64][64];   // [k][col]
  int tid = threadIdx.x;
  int row0 = blockIdx.x * 64;
  int rg = tid >> 4, cg = tid & 15;
  float acc[4][4] = {};
  for (int kc = 0; kc < 256; kc += 64) {
    int rr = tid >> 4, kq = tid & 15;
#pragma unroll
    for (int p = 0; p < 4; ++p) {
      int r = rr + p * 16;
      int grow = row0 + r;
      float4 v = make_float4(0.f, 0.f, 0.f, 0.f);
      if (grow < N) v = *(const float4*)&x[(size_t)grow * 256 + kc + kq * 4];
      xs[kq * 4 + 0][r] = v.x; xs[kq * 4 + 1][r] = v.y;
      xs[kq * 4 + 2][r] = v.z; xs[kq * 4 + 3][r] = v.w;
      *(float4*)&wl[r][kq * 4] = *(const float4*)&W[(size_t)(kc + r) * 64 + kq * 4];
    }
    __syncthreads();
#pragma unroll 4
    for (int k = 0; k < 64; ++k) {
      float4 xv = *(const float4*)&xs[k][rg * 4];
      float4 wv = *(const float4*)&wl[k][cg * 4];
      float xa[4] = {xv.x, xv.y, xv.z, xv.w};
      float wa[4] = {wv.x, wv.y, wv.z, wv.w};
#pragma unroll
      for (int i = 0; i < 4; ++i)
#pragma unroll
        for (int j = 0; j < 4; ++j) acc[i][j] += xa[i] * wa[j];
    }
    __syncthreads();
  }
  float av[4], bv[4];
#pragma unroll
  for (int j = 0; j < 4; ++j) { av[j] = av_s[cg * 4 + j]; bv[j] = av_d[cg * 4 + j]; }
#pragma unroll
  for (int i = 0; i < 4; ++i) {
    int row = row0 + rg * 4 + i;
    if (row < N) {
      float4 o; o.x = acc[i][0]; o.y = acc[i][1]; o.z = acc[i][2]; o.w = acc[i][3];
      *(float4*)&h1[(size_t)row * 64 + cg * 4] = o;
      float ps = acc[i][0] * av[0] + acc[i][1] * av[1] + acc[i][2] * av[2] + acc[i][3] * av[3];
      float pd = acc[i][0] * bv[0] + acc[i][1] * bv[1] + acc[i][2] * bv[2] + acc[i][3] * bv[3];
      ps += __shfl_xor(ps, 1);
      pd += __shfl_xor(pd, 1);
      if ((cg & 1) == 0) {
        as1[row * 8 + (cg >> 1)] = ps;
        ad1[row * 8 + (cg >> 1)] = pd;
      }
    }
  }
}

// ---- Layer 1 aggregate: chunked online softmax, 8 heads x 8 lanes ---------

__global__ __launch_bounds__(256) void k_agg1(const int* __restrict__ csr, const int* __restrict__ offs,
                                              const float* __restrict__ h1, const float* __restrict__ as1,
                                              const float* __restrict__ ad1, const float* __restrict__ b1,
                                              float* __restrict__ helu, int N) {
  __shared__ float wsm[4][8][66];
  __shared__ int   scs[4][64];
  int tid = threadIdx.x;
  int slot = tid >> 6;
  int node = blockIdx.x * 4 + slot;
  if (node >= N) return;
  int lane = tid & 63;
  int h = lane >> 3, cl = lane & 7;
  int beg = offs[node], end = offs[node + 1];
  int deg = end - beg;
  float adv = ad1[node * 8 + h];
  float m = -1e30f, denom = 0.f, acc = 0.f;
  for (int c0 = 0; c0 < deg; c0 += 64) {
    int cn = min(64, deg - c0);
    if (lane < cn) scs[slot][lane] = csr[beg + c0 + lane];
    float cmax = -1e30f;
    for (int i = cl; i < cn; i += 8) {
      int s = scs[slot][i];
      float v = lrelu02(as1[s * 8 + h] + adv);
      wsm[slot][h][i] = v;
      cmax = fmaxf(cmax, v);
    }
    cmax = fmaxf(cmax, __shfl_xor(cmax, 1));
    cmax = fmaxf(cmax, __shfl_xor(cmax, 2));
    cmax = fmaxf(cmax, __shfl_xor(cmax, 4));
    float mnew = fmaxf(m, cmax);
    float sc = __expf(m - mnew);
    denom *= sc; acc *= sc; m = mnew;
    float dp = 0.f;
    for (int i = cl; i < cn; i += 8) {
      float wv = __expf(wsm[slot][h][i] - m);
      wsm[slot][h][i] = wv;
      dp += wv;
    }
    dp += __shfl_xor(dp, 1);
    dp += __shfl_xor(dp, 2);
    dp += __shfl_xor(dp, 4);
    denom += dp;
    int i = 0;
    for (; i + 4 <= cn; i += 4) {
      float w0 = wsm[slot][h][i + 0], w1 = wsm[slot][h][i + 1];
      float w2 = wsm[slot][h][i + 2], w3 = wsm[slot][h][i + 3];
      int s0 = scs[slot][i + 0], s1 = scs[slot][i + 1];
      int s2 = scs[slot][i + 2], s3 = scs[slot][i + 3];
      acc += w0 * h1[(size_t)s0 * 64 + lane];
      acc += w1 * h1[(size_t)s1 * 64 + lane];
      acc += w2 * h1[(size_t)s2 * 64 + lane];
      acc += w3 * h1[(size_t)s3 * 64 + lane];
    }
    for (; i < cn; ++i) {
      float wv = wsm[slot][h][i];
      int s = scs[slot][i];
      acc += wv * h1[(size_t)s * 64 + lane];
    }
  }
  float o = acc / denom + b1[lane];
  o = o > 0.f ? o : expm1f(o);   // ELU(alpha=1)
  helu[(size_t)node * 64 + lane] = o;
}

// ---- Layer 2 GEMM: h2 = helu @ W2  [N,64]@[64,100] ------------------------

__global__ __launch_bounds__(256) void k_gemm2(const float* __restrict__ he, const float* __restrict__ W2,
                                               float* __restrict__ h2, int N) {
  __shared__ float het[64][44];     // [k][row]
  __shared__ float w2l[64 * 100];   // [k][col]
  int tid = threadIdx.x;
  int row0 = blockIdx.x * 40;
  for (int i = tid; i < 6400; i += 256) w2l[i] = W2[i];
  for (int idx = tid; idx < 640; idx += 256) {
    int r = idx >> 4, kq = idx & 15;
    int grow = row0 + r;
    float4 v = make_float4(0.f, 0.f, 0.f, 0.f);
    if (grow < N) v = *(const float4*)&he[(size_t)grow * 64 + kq * 4];
    het[kq * 4 + 0][r] = v.x; het[kq * 4 + 1][r] = v.y;
    het[kq * 4 + 2][r] = v.z; het[kq * 4 + 3][r] = v.w;
  }
  __syncthreads();
  int rg = tid / 25, cg = tid % 25;
  if (rg >= 10) return;
  float acc[4][4] = {};
#pragma unroll 4
  for (int k = 0; k < 64; ++k) {
    float4 xv = *(const float4*)&het[k][rg * 4];
    float4 wv = *(const float4*)&w2l[k * 100 + cg * 4];
    float xa[4] = {xv.x, xv.y, xv.z, xv.w};
    float wa[4] = {wv.x, wv.y, wv.z, wv.w};
#pragma unroll
    for (int i = 0; i < 4; ++i)
#pragma unroll
      for (int j = 0; j < 4; ++j) acc[i][j] += xa[i] * wa[j];
  }
#pragma unroll
  for (int i = 0; i < 4; ++i) {
    int row = row0 + rg * 4 + i;
    if (row < N) {
      float4 o; o.x = acc[i][0]; o.y = acc[i][1]; o.z = acc[i][2]; o.w = acc[i][3];
      *(float4*)&h2[(size_t)row * 100 + cg * 4] = o;
    }
  }
}

// ---- Layer 2 alpha --------------------------------------------------------

__global__ __launch_bounds__(256) void k_alpha2(const float* __restrict__ h2, const float* __restrict__ a2s,
                                                const float* __restrict__ a2d, float* __restrict__ as2,
                                                float* __restrict__ ad2, int N) {
  int tid = threadIdx.x;
  int node = blockIdx.x * 4 + (tid >> 6);
  if (node >= N) return;
  int lane = tid & 63;
  float v = h2[(size_t)node * 100 + lane];
  float s = v * a2s[lane];
  float d = v * a2d[lane];
  if (lane < 36) {
    float v2 = h2[(size_t)node * 100 + 64 + lane];
    s += v2 * a2s[64 + lane];
    d += v2 * a2d[64 + lane];
  }
#pragma unroll
  for (int off = 32; off; off >>= 1) { s += __shfl_xor(s, off); d += __shfl_xor(d, off); }
  if (lane == 0) { as2[node] = s; ad2[node] = d; }
}

// ---- Layer 2 aggregate: chunked online softmax + sigmoid ------------------

__global__ __launch_bounds__(256) void k_agg2(const int* __restrict__ csr, const int* __restrict__ offs,
                                              const float* __restrict__ h2, const float* __restrict__ as2,
                                              const float* __restrict__ ad2, const float* __restrict__ b2,
                                              float* __restrict__ out, int N) {
  __shared__ float2 lds2[4][64];
  int tid = threadIdx.x;
  int slot = tid >> 6;
  int node = blockIdx.x * 4 + slot;
  if (node >= N) return;
  int lane = tid & 63;
  int beg = offs[node], end = offs[node + 1];
  int deg = end - beg;
  float adv = ad2[node];
  bool two = lane < 36;
  float m = -1e30f, denom = 0.f, acc0 = 0.f, acc1 = 0.f;
  for (int c0 = 0; c0 < deg; c0 += 64) {
    int cn = min(64, deg - c0);
    int sreg = 0; float v = -1e30f;
    if (lane < cn) {
      sreg = csr[beg + c0 + lane];
      v = lrelu02(as2[sreg] + adv);
    }
    float cm = v;
#pragma unroll
    for (int off = 32; off; off >>= 1) cm = fmaxf(cm, __shfl_xor(cm, off));
    float mnew = fmaxf(m, cm);
    float sc = __expf(m - mnew);
    denom *= sc; acc0 *= sc; acc1 *= sc; m = mnew;
    float w = (lane < cn) ? __expf(v - m) : 0.f;
    lds2[slot][lane] = make_float2(w, __int_as_float(sreg));
    float dp = w;
#pragma unroll
    for (int off = 32; off; off >>= 1) dp += __shfl_xor(dp, off);
    denom += dp;
    int i = 0;
    for (; i + 4 <= cn; i += 4) {
      float2 e0 = lds2[slot][i + 0];
      float2 e1 = lds2[slot][i + 1];
      float2 e2 = lds2[slot][i + 2];
      float2 e3 = lds2[slot][i + 3];
      const float* r0 = h2 + (size_t)__float_as_int(e0.y) * 100;
      const float* r1 = h2 + (size_t)__float_as_int(e1.y) * 100;
      const float* r2 = h2 + (size_t)__float_as_int(e2.y) * 100;
      const float* r3 = h2 + (size_t)__float_as_int(e3.y) * 100;
      acc0 += e0.x * r0[lane];
      acc0 += e1.x * r1[lane];
      acc0 += e2.x * r2[lane];
      acc0 += e3.x * r3[lane];
      if (two) {
        acc1 += e0.x * r0[64 + lane];
        acc1 += e1.x * r1[64 + lane];
        acc1 += e2.x * r2[64 + lane];
        acc1 += e3.x * r3[64 + lane];
      }
    }
    for (; i < cn; ++i) {
      float2 e0 = lds2[slot][i];
      const float* r0 = h2 + (size_t)__float_as_int(e0.y) * 100;
      acc0 += e0.x * r0[lane];
      if (two) acc1 += e0.x * r0[64 + lane];
    }
  }
  float r = 1.f / denom;
  out[(size_t)node * 100 + lane] = 1.f / (1.f + __expf(-(acc0 * r + b2[lane])));
  if (two)
    out[(size_t)node * 100 + 64 + lane] = 1.f / (1.f + __expf(-(acc1 * r + b2[64 + lane])));
}

// ---------------------------------------------------------------------------

extern "C" void kernel_launch(void* const* d_in, const int* in_sizes, int n_in,
                              void* d_out, int out_size, void* d_ws, size_t ws_size,
                              hipStream_t stream) {
  const float* x    = (const float*)d_in[0];
  const int*   ei   = (const int*)d_in[1];    // harness converts integer inputs to int32
  const float* W1   = (const float*)d_in[2];
  const float* a_s1 = (const float*)d_in[3];
  const float* a_d1 = (const float*)d_in[4];
  const float* b1   = (const float*)d_in[5];
  const float* W2   = (const float*)d_in[6];
  const float* a_s2 = (const float*)d_in[7];
  const float* a_d2 = (const float*)d_in[8];
  const float* b2   = (const float*)d_in[9];
  float* out = (float*)d_out;

  const int N = in_sizes[0] / 256;
  const int E = in_sizes[1] / 2;
  const int EP = E + N;
  const int K = (N + BNN - 1) >> BSH;       // buckets (<=256 for N<=131072)

  char* w = (char*)d_ws;
  size_t off = 0;
  auto alloc = [&](size_t bytes) -> char* {
    char* p = w + off;
    off = (off + bytes + 255) & ~(size_t)255;
    return p;
  };
  float* h12  = (float*)alloc((size_t)N * 100 * 4);  // h1 uses N*64, h2 uses N*100
  float* h1   = h12;
  float* h2   = h12;
  float* helu = (float*)alloc((size_t)N * 64 * 4);
  float* as1  = (float*)alloc((size_t)N * 8 * 4);
  float* ad1  = (float*)alloc((size_t)N * 8 * 4);
  float* as2  = (float*)alloc((size_t)N * 4);
  float* ad2  = (float*)alloc((size_t)N * 4);
  int*   offs   = (int*)alloc((size_t)(N + 1) * 4);
  int*   csr    = (int*)alloc((size_t)EP * 4);
  int2*  binned = (int2*)alloc((size_t)E * 8);
  int*   bhist  = (int*)alloc((size_t)(K + 1) * 4);
  int*   bbase  = (int*)alloc((size_t)(K + 1) * 4);
  int*   bcur   = (int*)alloc((size_t)K * 4);
  (void)ws_size; (void)n_in; (void)out_size;

  hipMemsetAsync(bhist, 0, (size_t)K * 4, stream);

  int ebl = (E + 2047) / 2048;
  k_hist<<<ebl, 256, 0, stream>>>(ei, E, bhist);
  k_bscan<<<1, 256, 0, stream>>>(bhist, bbase, bcur, offs, K, E, N);
  k_bin<<<ebl, 256, 0, stream>>>(ei, E, bcur, binned);
  k_bucket<<<K, 256, 0, stream>>>(binned, bbase, offs, csr, N);

  k_gemm1<<<(N + 63) / 64, 256, 0, stream>>>(x, W1, a_s1, a_d1, h1, as1, ad1, N);
  k_agg1<<<(N + 3) / 4, 256, 0, stream>>>(csr, offs, h1, as1, ad1, b1, helu, N);

  k_gemm2<<<(N + 39) / 40, 256, 0, stream>>>(helu, W2, h2, N);
  k_alpha2<<<(N + 3) / 4, 256, 0, stream>>>(h2, a_s2, a_d2, as2, ad2, N);
  k_agg2<<<(N + 3) / 4, 256, 0, stream>>>(csr, offs, h2, as2, ad2, b2, out, N);
}

// Round 5
// 313.248 us; speedup vs baseline: 2.3670x; 1.2107x over previous
//
#include <hip/hip_runtime.h>
#include <hip/hip_bf16.h>
#include <cmath>

// ---------------------------------------------------------------------------
// GAT 2-layer forward.
// CSR build via 2-level bucketing. Layer1: fp32 GEMM (bf16 h1 out) -> agg1
// (online softmax, bf16 gather) fused with helu-bf16 write + as2/ad2
// projection (as2 = helu . (W2@a_src2) -- linearity). Layer2: aggregate helu
// (64ch bf16) then GEMM W2 + bias + sigmoid. No h2 materialization.
// ---------------------------------------------------------------------------

#define BSH 9                 // 512 nodes per bucket; requires N <= 131072
#define BNN (1 << BSH)

__device__ __forceinline__ float lrelu02(float v) { return v > 0.f ? v : 0.2f * v; }

__device__ __forceinline__ float b2f(unsigned short u) {
  union { float f; unsigned int i; } c; c.i = ((unsigned int)u) << 16; return c.f;
}
__device__ __forceinline__ unsigned short f2b(float f) {
  union { float f; unsigned int i; } c; c.f = f;
  unsigned int r = c.i + 0x7FFFu + ((c.i >> 16) & 1u);   // RNE
  return (unsigned short)(r >> 16);
}

// ---- CSR build: pass A1 — bucket histogram --------------------------------

__global__ __launch_bounds__(256) void k_hist(const int* __restrict__ ei, int E,
                                              int* __restrict__ bhist) {
  __shared__ int lh[256];
  int tid = threadIdx.x;
  lh[tid] = 0;
  __syncthreads();
  int base = blockIdx.x * 2048;
#pragma unroll
  for (int j = 0; j < 8; ++j) {
    int e = base + j * 256 + tid;
    if (e < E) atomicAdd(&lh[ei[E + e] >> BSH], 1);
  }
  __syncthreads();
  if (lh[tid]) atomicAdd(&bhist[tid], lh[tid]);
}

// ---- pass A2 — scan bucket counts (single block) --------------------------

__global__ __launch_bounds__(256) void k_bscan(const int* __restrict__ bhist,
                                               int* __restrict__ bbase, int* __restrict__ bcur,
                                               int* __restrict__ offs, int K, int E, int N) {
  __shared__ int s[256];
  int tid = threadIdx.x;
  int v = (tid < K) ? bhist[tid] : 0;
  s[tid] = v;
  __syncthreads();
  for (int off = 1; off < 256; off <<= 1) {
    int t = (tid >= off) ? s[tid - off] : 0;
    __syncthreads();
    s[tid] += t;
    __syncthreads();
  }
  int excl = s[tid] - v;
  if (tid < K) { bbase[tid] = excl; bcur[tid] = excl; }
  if (tid == 255) bbase[K] = s[255];    // = E
  if (tid == 0) offs[N] = E + N;
}

// ---- pass A3 — bin edges into buckets as (src, dst_local) -----------------

__global__ __launch_bounds__(256) void k_bin(const int* __restrict__ ei, int E,
                                             int* __restrict__ bcur, int2* __restrict__ binned) {
  __shared__ int lh[256];
  __shared__ int lbase[256];
  int tid = threadIdx.x;
  lh[tid] = 0;
  __syncthreads();
  int base = blockIdx.x * 2048;
  int bj[8], rk[8], sj[8], dl[8];
#pragma unroll
  for (int j = 0; j < 8; ++j) {
    int e = base + j * 256 + tid;
    bj[j] = -1;
    if (e < E) {
      sj[j] = ei[e];
      int d = ei[E + e];
      bj[j] = d >> BSH;
      dl[j] = d & (BNN - 1);
      rk[j] = atomicAdd(&lh[bj[j]], 1);
    }
  }
  __syncthreads();
  if (lh[tid]) lbase[tid] = atomicAdd(&bcur[tid], lh[tid]);
  __syncthreads();
#pragma unroll
  for (int j = 0; j < 8; ++j)
    if (bj[j] >= 0) binned[lbase[bj[j]] + rk[j]] = make_int2(sj[j], dl[j]);
}

// ---- pass B — per-bucket CSR fill (one block per bucket) ------------------

__global__ __launch_bounds__(256) void k_bucket(const int2* __restrict__ binned,
                                                const int* __restrict__ bbase,
                                                int* __restrict__ offs, int* __restrict__ csr,
                                                int N) {
  __shared__ int hist[BNN], loffS[BNN], cur[BNN];
  __shared__ int s[256];
  int tid = threadIdx.x;
  int b = blockIdx.x;
  int node0 = b << BSH;
  int sl = min(BNN, N - node0);
  int e0 = bbase[b], e1 = bbase[b + 1];
  int cbase = e0 + min(node0, N);          // csr base incl. upstream self-loops
  hist[tid] = 0; hist[tid + 256] = 0;
  __syncthreads();
  for (int e = e0 + tid; e < e1; e += 256) atomicAdd(&hist[binned[e].y], 1);
  __syncthreads();
  int a0 = hist[2 * tid], a1 = hist[2 * tid + 1];
  s[tid] = a0 + a1;
  __syncthreads();
  for (int off = 1; off < 256; off <<= 1) {
    int t = (tid >= off) ? s[tid - off] : 0;
    __syncthreads();
    s[tid] += t;
    __syncthreads();
  }
  int excl = s[tid] - (a0 + a1);
  loffS[2 * tid]     = excl + 2 * tid;
  loffS[2 * tid + 1] = excl + a0 + 2 * tid + 1;
  __syncthreads();
  cur[2 * tid] = loffS[2 * tid];
  cur[2 * tid + 1] = loffS[2 * tid + 1];
  if (2 * tid < sl)     offs[node0 + 2 * tid]     = cbase + loffS[2 * tid];
  if (2 * tid + 1 < sl) offs[node0 + 2 * tid + 1] = cbase + loffS[2 * tid + 1];
  __syncthreads();
  for (int e = e0 + tid; e < e1; e += 256) {
    int2 u = binned[e];
    int p = atomicAdd(&cur[u.y], 1);
    csr[cbase + p] = u.x;
  }
  for (int i = tid; i < sl; i += 256) {
    int p = atomicAdd(&cur[i], 1);
    csr[cbase + p] = node0 + i;            // self loop
  }
}

// ---- projection of layer-2 attention vectors through W2 -------------------
// w2as[c] = sum_k W2[c,k] * a2s[k];  w2ad[c] = sum_k W2[c,k] * a2d[k]

__global__ __launch_bounds__(128) void k_proj(const float* __restrict__ W2,
                                              const float* __restrict__ a2s,
                                              const float* __restrict__ a2d,
                                              float* __restrict__ w2as, float* __restrict__ w2ad) {
  int t = threadIdx.x;
  if (t < 64) {
    float s = 0.f;
    for (int k = 0; k < 100; ++k) s += W2[t * 100 + k] * a2s[k];
    w2as[t] = s;
  } else {
    int c = t - 64;
    float s = 0.f;
    for (int k = 0; k < 100; ++k) s += W2[c * 100 + k] * a2d[k];
    w2ad[c] = s;
  }
}

// ---- Layer 1 GEMM: h1 = x @ W1 (bf16 out), fused alpha_s/alpha_d ----------

__global__ __launch_bounds__(256) void k_gemm1(const float* __restrict__ x, const float* __restrict__ W,
                                               const float* __restrict__ av_s, const float* __restrict__ av_d,
                                               unsigned short* __restrict__ h1b, float* __restrict__ as1,
                                               float* __restrict__ ad1, int N) {
  __shared__ float xs[64][68];   // [k][row]
  __shared__ float wl[64][64];   // [k][col]
  int tid = threadIdx.x;
  int row0 = blockIdx.x * 64;
  int rg = tid >> 4, cg = tid & 15;
  float acc[4][4] = {};
  for (int kc = 0; kc < 256; kc += 64) {
    int rr = tid >> 4, kq = tid & 15;
#pragma unroll
    for (int p = 0; p < 4; ++p) {
      int r = rr + p * 16;
      int grow = row0 + r;
      float4 v = make_float4(0.f, 0.f, 0.f, 0.f);
      if (grow < N) v = *(const float4*)&x[(size_t)grow * 256 + kc + kq * 4];
      xs[kq * 4 + 0][r] = v.x; xs[kq * 4 + 1][r] = v.y;
      xs[kq * 4 + 2][r] = v.z; xs[kq * 4 + 3][r] = v.w;
      *(float4*)&wl[r][kq * 4] = *(const float4*)&W[(size_t)(kc + r) * 64 + kq * 4];
    }
    __syncthreads();
#pragma unroll 4
    for (int k = 0; k < 64; ++k) {
      float4 xv = *(const float4*)&xs[k][rg * 4];
      float4 wv = *(const float4*)&wl[k][cg * 4];
      float xa[4] = {xv.x, xv.y, xv.z, xv.w};
      float wa[4] = {wv.x, wv.y, wv.z, wv.w};
#pragma unroll
      for (int i = 0; i < 4; ++i)
#pragma unroll
        for (int j = 0; j < 4; ++j) acc[i][j] += xa[i] * wa[j];
    }
    __syncthreads();
  }
  float av[4], bv[4];
#pragma unroll
  for (int j = 0; j < 4; ++j) { av[j] = av_s[cg * 4 + j]; bv[j] = av_d[cg * 4 + j]; }
#pragma unroll
  for (int i = 0; i < 4; ++i) {
    int row = row0 + rg * 4 + i;
    if (row < N) {
      ushort4 o;
      o.x = f2b(acc[i][0]); o.y = f2b(acc[i][1]);
      o.z = f2b(acc[i][2]); o.w = f2b(acc[i][3]);
      *(ushort4*)&h1b[(size_t)row * 64 + cg * 4] = o;
      float ps = acc[i][0] * av[0] + acc[i][1] * av[1] + acc[i][2] * av[2] + acc[i][3] * av[3];
      float pd = acc[i][0] * bv[0] + acc[i][1] * bv[1] + acc[i][2] * bv[2] + acc[i][3] * bv[3];
      ps += __shfl_xor(ps, 1);
      pd += __shfl_xor(pd, 1);
      if ((cg & 1) == 0) {
        as1[row * 8 + (cg >> 1)] = ps;
        ad1[row * 8 + (cg >> 1)] = pd;
      }
    }
  }
}

// ---- Layer 1 aggregate + ELU + helu-bf16 write + as2/ad2 projection -------

__global__ __launch_bounds__(256) void k_agg1(const int* __restrict__ csr, const int* __restrict__ offs,
                                              const unsigned short* __restrict__ h1b,
                                              const float* __restrict__ as1, const float* __restrict__ ad1,
                                              const float* __restrict__ b1,
                                              const float* __restrict__ w2as, const float* __restrict__ w2ad,
                                              unsigned short* __restrict__ helu_b,
                                              float* __restrict__ as2, float* __restrict__ ad2, int N) {
  __shared__ float wsm[4][8][66];
  __shared__ int   scs[4][64];
  int tid = threadIdx.x;
  int slot = tid >> 6;
  int node = blockIdx.x * 4 + slot;
  if (node >= N) return;
  int lane = tid & 63;
  int h = lane >> 3, cl = lane & 7;
  int beg = offs[node], end = offs[node + 1];
  int deg = end - beg;
  float adv = ad1[node * 8 + h];
  float m = -1e30f, denom = 0.f, acc = 0.f;
  for (int c0 = 0; c0 < deg; c0 += 64) {
    int cn = min(64, deg - c0);
    if (lane < cn) scs[slot][lane] = csr[beg + c0 + lane];
    float cmax = -1e30f;
    for (int i = cl; i < cn; i += 8) {
      int s = scs[slot][i];
      float v = lrelu02(as1[s * 8 + h] + adv);
      wsm[slot][h][i] = v;
      cmax = fmaxf(cmax, v);
    }
    cmax = fmaxf(cmax, __shfl_xor(cmax, 1));
    cmax = fmaxf(cmax, __shfl_xor(cmax, 2));
    cmax = fmaxf(cmax, __shfl_xor(cmax, 4));
    float mnew = fmaxf(m, cmax);
    float sc = __expf(m - mnew);
    denom *= sc; acc *= sc; m = mnew;
    float dp = 0.f;
    for (int i = cl; i < cn; i += 8) {
      float wv = __expf(wsm[slot][h][i] - m);
      wsm[slot][h][i] = wv;
      dp += wv;
    }
    dp += __shfl_xor(dp, 1);
    dp += __shfl_xor(dp, 2);
    dp += __shfl_xor(dp, 4);
    denom += dp;
    int i = 0;
    for (; i + 4 <= cn; i += 4) {
      float w0 = wsm[slot][h][i + 0], w1 = wsm[slot][h][i + 1];
      float w2 = wsm[slot][h][i + 2], w3 = wsm[slot][h][i + 3];
      int s0 = scs[slot][i + 0], s1 = scs[slot][i + 1];
      int s2 = scs[slot][i + 2], s3 = scs[slot][i + 3];
      acc += w0 * b2f(h1b[(size_t)s0 * 64 + lane]);
      acc += w1 * b2f(h1b[(size_t)s1 * 64 + lane]);
      acc += w2 * b2f(h1b[(size_t)s2 * 64 + lane]);
      acc += w3 * b2f(h1b[(size_t)s3 * 64 + lane]);
    }
    for (; i < cn; ++i) {
      float wv = wsm[slot][h][i];
      int s = scs[slot][i];
      acc += wv * b2f(h1b[(size_t)s * 64 + lane]);
    }
  }
  float o = acc / denom + b1[lane];
  o = o > 0.f ? o : expm1f(o);   // ELU(alpha=1)
  helu_b[(size_t)node * 64 + lane] = f2b(o);
  // fused layer-2 alpha: as2 = helu . (W2 @ a_src2), ad2 likewise (fp32 exact)
  float s2 = o * w2as[lane];
  float d2 = o * w2ad[lane];
#pragma unroll
  for (int off = 32; off; off >>= 1) { s2 += __shfl_xor(s2, off); d2 += __shfl_xor(d2, off); }
  if (lane == 0) { as2[node] = s2; ad2[node] = d2; }
}

// ---- Layer 2 aggregate over helu (64 ch, bf16): agg = sum alpha*helu ------

__global__ __launch_bounds__(256) void k_agg2(const int* __restrict__ csr, const int* __restrict__ offs,
                                              const unsigned short* __restrict__ helu_b,
                                              const float* __restrict__ as2, const float* __restrict__ ad2,
                                              float* __restrict__ agg, int N) {
  __shared__ float2 lds2[4][64];
  int tid = threadIdx.x;
  int slot = tid >> 6;
  int node = blockIdx.x * 4 + slot;
  if (node >= N) return;
  int lane = tid & 63;
  int beg = offs[node], end = offs[node + 1];
  int deg = end - beg;
  float adv = ad2[node];
  float m = -1e30f, denom = 0.f, acc = 0.f;
  for (int c0 = 0; c0 < deg; c0 += 64) {
    int cn = min(64, deg - c0);
    int sreg = 0; float v = -1e30f;
    if (lane < cn) {
      sreg = csr[beg + c0 + lane];
      v = lrelu02(as2[sreg] + adv);
    }
    float cm = v;
#pragma unroll
    for (int off = 32; off; off >>= 1) cm = fmaxf(cm, __shfl_xor(cm, off));
    float mnew = fmaxf(m, cm);
    float sc = __expf(m - mnew);
    denom *= sc; acc *= sc; m = mnew;
    float w = (lane < cn) ? __expf(v - m) : 0.f;
    lds2[slot][lane] = make_float2(w, __int_as_float(sreg));
    float dp = w;
#pragma unroll
    for (int off = 32; off; off >>= 1) dp += __shfl_xor(dp, off);
    denom += dp;
    int i = 0;
    for (; i + 4 <= cn; i += 4) {
      float2 e0 = lds2[slot][i + 0];
      float2 e1 = lds2[slot][i + 1];
      float2 e2 = lds2[slot][i + 2];
      float2 e3 = lds2[slot][i + 3];
      acc += e0.x * b2f(helu_b[(size_t)__float_as_int(e0.y) * 64 + lane]);
      acc += e1.x * b2f(helu_b[(size_t)__float_as_int(e1.y) * 64 + lane]);
      acc += e2.x * b2f(helu_b[(size_t)__float_as_int(e2.y) * 64 + lane]);
      acc += e3.x * b2f(helu_b[(size_t)__float_as_int(e3.y) * 64 + lane]);
    }
    for (; i < cn; ++i) {
      float2 e0 = lds2[slot][i];
      acc += e0.x * b2f(helu_b[(size_t)__float_as_int(e0.y) * 64 + lane]);
    }
  }
  agg[(size_t)node * 64 + lane] = acc / denom;
}

// ---- Final GEMM: out = sigmoid(agg @ W2 + b2)  [N,64]@[64,100] ------------

__global__ __launch_bounds__(256) void k_gemm2b(const float* __restrict__ agg, const float* __restrict__ W2,
                                                const float* __restrict__ b2, float* __restrict__ out, int N) {
  __shared__ float het[64][44];     // [k][row]
  __shared__ float w2l[64 * 100];   // [k][col]
  int tid = threadIdx.x;
  int row0 = blockIdx.x * 40;
  for (int i = tid; i < 6400; i += 256) w2l[i] = W2[i];
  for (int idx = tid; idx < 640; idx += 256) {
    int r = idx >> 4, kq = idx & 15;
    int grow = row0 + r;
    float4 v = make_float4(0.f, 0.f, 0.f, 0.f);
    if (grow < N) v = *(const float4*)&agg[(size_t)grow * 64 + kq * 4];
    het[kq * 4 + 0][r] = v.x; het[kq * 4 + 1][r] = v.y;
    het[kq * 4 + 2][r] = v.z; het[kq * 4 + 3][r] = v.w;
  }
  __syncthreads();
  int rg = tid / 25, cg = tid % 25;
  if (rg >= 10) return;
  float acc[4][4] = {};
#pragma unroll 4
  for (int k = 0; k < 64; ++k) {
    float4 xv = *(const float4*)&het[k][rg * 4];
    float4 wv = *(const float4*)&w2l[k * 100 + cg * 4];
    float xa[4] = {xv.x, xv.y, xv.z, xv.w};
    float wa[4] = {wv.x, wv.y, wv.z, wv.w};
#pragma unroll
    for (int i = 0; i < 4; ++i)
#pragma unroll
      for (int j = 0; j < 4; ++j) acc[i][j] += xa[i] * wa[j];
  }
  float bb[4];
#pragma unroll
  for (int j = 0; j < 4; ++j) bb[j] = b2[cg * 4 + j];
#pragma unroll
  for (int i = 0; i < 4; ++i) {
    int row = row0 + rg * 4 + i;
    if (row < N) {
      float4 o;
      o.x = 1.f / (1.f + __expf(-(acc[i][0] + bb[0])));
      o.y = 1.f / (1.f + __expf(-(acc[i][1] + bb[1])));
      o.z = 1.f / (1.f + __expf(-(acc[i][2] + bb[2])));
      o.w = 1.f / (1.f + __expf(-(acc[i][3] + bb[3])));
      *(float4*)&out[(size_t)row * 100 + cg * 4] = o;
    }
  }
}

// ---------------------------------------------------------------------------

extern "C" void kernel_launch(void* const* d_in, const int* in_sizes, int n_in,
                              void* d_out, int out_size, void* d_ws, size_t ws_size,
                              hipStream_t stream) {
  const float* x    = (const float*)d_in[0];
  const int*   ei   = (const int*)d_in[1];    // harness converts integer inputs to int32
  const float* W1   = (const float*)d_in[2];
  const float* a_s1 = (const float*)d_in[3];
  const float* a_d1 = (const float*)d_in[4];
  const float* b1   = (const float*)d_in[5];
  const float* W2   = (const float*)d_in[6];
  const float* a_s2 = (const float*)d_in[7];
  const float* a_d2 = (const float*)d_in[8];
  const float* b2   = (const float*)d_in[9];
  float* out = (float*)d_out;

  const int N = in_sizes[0] / 256;
  const int E = in_sizes[1] / 2;
  const int K = (N + BNN - 1) >> BSH;       // buckets (<=256 for N<=131072)

  char* w = (char*)d_ws;
  size_t off = 0;
  auto alloc = [&](size_t bytes) -> char* {
    char* p = w + off;
    off = (off + bytes + 255) & ~(size_t)255;
    return p;
  };
  unsigned short* h1b    = (unsigned short*)alloc((size_t)N * 64 * 2);
  unsigned short* helu_b = (unsigned short*)alloc((size_t)N * 64 * 2);
  float* agg  = (float*)alloc((size_t)N * 64 * 4);
  float* as1  = (float*)alloc((size_t)N * 8 * 4);
  float* ad1  = (float*)alloc((size_t)N * 8 * 4);
  float* as2  = (float*)alloc((size_t)N * 4);
  float* ad2  = (float*)alloc((size_t)N * 4);
  float* w2as = (float*)alloc(64 * 4);
  float* w2ad = (float*)alloc(64 * 4);
  int*   offs   = (int*)alloc((size_t)(N + 1) * 4);
  int*   csr    = (int*)alloc((size_t)(E + N) * 4);
  int2*  binned = (int2*)alloc((size_t)E * 8);
  int*   bhist  = (int*)alloc((size_t)(K + 1) * 4);
  int*   bbase  = (int*)alloc((size_t)(K + 1) * 4);
  int*   bcur   = (int*)alloc((size_t)K * 4);
  (void)ws_size; (void)n_in; (void)out_size;

  hipMemsetAsync(bhist, 0, (size_t)K * 4, stream);

  int ebl = (E + 2047) / 2048;
  k_hist<<<ebl, 256, 0, stream>>>(ei, E, bhist);
  k_bscan<<<1, 256, 0, stream>>>(bhist, bbase, bcur, offs, K, E, N);
  k_bin<<<ebl, 256, 0, stream>>>(ei, E, bcur, binned);
  k_bucket<<<K, 256, 0, stream>>>(binned, bbase, offs, csr, N);

  k_proj<<<1, 128, 0, stream>>>(W2, a_s2, a_d2, w2as, w2ad);
  k_gemm1<<<(N + 63) / 64, 256, 0, stream>>>(x, W1, a_s1, a_d1, h1b, as1, ad1, N);
  k_agg1<<<(N + 3) / 4, 256, 0, stream>>>(csr, offs, h1b, as1, ad1, b1, w2as, w2ad,
                                          helu_b, as2, ad2, N);
  k_agg2<<<(N + 3) / 4, 256, 0, stream>>>(csr, offs, helu_b, as2, ad2, agg, N);
  k_gemm2b<<<(N + 39) / 40, 256, 0, stream>>>(agg, W2, b2, out, N);
}

// Round 6
// 306.580 us; speedup vs baseline: 2.4185x; 1.0217x over previous
//
#include <hip/hip_runtime.h>
#include <hip/hip_bf16.h>
#include <cmath>

// ---------------------------------------------------------------------------
// GAT 2-layer forward.
// CSR build via 2-level bucketing. Layer1: fp32 GEMM (bf16 h1 out) -> agg1
// (max-free softmax: exp directly, shift-invariance; data range |e|<~7) fused
// with helu-bf16 write + as2/ad2 projection. Layer2: aggregate helu (64ch
// bf16) then GEMM W2 + bias + sigmoid.
// ---------------------------------------------------------------------------

#define BSH 9                 // 512 nodes per bucket; requires N <= 131072
#define BNN (1 << BSH)

__device__ __forceinline__ float lrelu02(float v) { return v > 0.f ? v : 0.2f * v; }

__device__ __forceinline__ float b2f(unsigned short u) {
  union { float f; unsigned int i; } c; c.i = ((unsigned int)u) << 16; return c.f;
}
__device__ __forceinline__ unsigned short f2b(float f) {
  union { float f; unsigned int i; } c; c.f = f;
  unsigned int r = c.i + 0x7FFFu + ((c.i >> 16) & 1u);   // RNE
  return (unsigned short)(r >> 16);
}

// ---- CSR build: pass A1 — bucket histogram --------------------------------

__global__ __launch_bounds__(256) void k_hist(const int* __restrict__ ei, int E,
                                              int* __restrict__ bhist) {
  __shared__ int lh[256];
  int tid = threadIdx.x;
  lh[tid] = 0;
  __syncthreads();
  int base = blockIdx.x * 2048;
#pragma unroll
  for (int j = 0; j < 8; ++j) {
    int e = base + j * 256 + tid;
    if (e < E) atomicAdd(&lh[ei[E + e] >> BSH], 1);
  }
  __syncthreads();
  if (lh[tid]) atomicAdd(&bhist[tid], lh[tid]);
}

// ---- pass A2 — scan bucket counts (single block) --------------------------

__global__ __launch_bounds__(256) void k_bscan(const int* __restrict__ bhist,
                                               int* __restrict__ bbase, int* __restrict__ bcur,
                                               int* __restrict__ offs, int K, int E, int N) {
  __shared__ int s[256];
  int tid = threadIdx.x;
  int v = (tid < K) ? bhist[tid] : 0;
  s[tid] = v;
  __syncthreads();
  for (int off = 1; off < 256; off <<= 1) {
    int t = (tid >= off) ? s[tid - off] : 0;
    __syncthreads();
    s[tid] += t;
    __syncthreads();
  }
  int excl = s[tid] - v;
  if (tid < K) { bbase[tid] = excl; bcur[tid] = excl; }
  if (tid == 255) bbase[K] = s[255];    // = E
  if (tid == 0) offs[N] = E + N;
}

// ---- pass A3 — bin edges into buckets as (src, dst_local) -----------------

__global__ __launch_bounds__(256) void k_bin(const int* __restrict__ ei, int E,
                                             int* __restrict__ bcur, int2* __restrict__ binned) {
  __shared__ int lh[256];
  __shared__ int lbase[256];
  int tid = threadIdx.x;
  lh[tid] = 0;
  __syncthreads();
  int base = blockIdx.x * 2048;
  int bj[8], rk[8], sj[8], dl[8];
#pragma unroll
  for (int j = 0; j < 8; ++j) {
    int e = base + j * 256 + tid;
    bj[j] = -1;
    if (e < E) {
      sj[j] = ei[e];
      int d = ei[E + e];
      bj[j] = d >> BSH;
      dl[j] = d & (BNN - 1);
      rk[j] = atomicAdd(&lh[bj[j]], 1);
    }
  }
  __syncthreads();
  if (lh[tid]) lbase[tid] = atomicAdd(&bcur[tid], lh[tid]);
  __syncthreads();
#pragma unroll
  for (int j = 0; j < 8; ++j)
    if (bj[j] >= 0) binned[lbase[bj[j]] + rk[j]] = make_int2(sj[j], dl[j]);
}

// ---- pass B — per-bucket CSR fill (one block per bucket) ------------------

__global__ __launch_bounds__(256) void k_bucket(const int2* __restrict__ binned,
                                                const int* __restrict__ bbase,
                                                int* __restrict__ offs, int* __restrict__ csr,
                                                int N) {
  __shared__ int hist[BNN], loffS[BNN], cur[BNN];
  __shared__ int s[256];
  int tid = threadIdx.x;
  int b = blockIdx.x;
  int node0 = b << BSH;
  int sl = min(BNN, N - node0);
  int e0 = bbase[b], e1 = bbase[b + 1];
  int cbase = e0 + min(node0, N);          // csr base incl. upstream self-loops
  hist[tid] = 0; hist[tid + 256] = 0;
  __syncthreads();
  for (int e = e0 + tid; e < e1; e += 256) atomicAdd(&hist[binned[e].y], 1);
  __syncthreads();
  int a0 = hist[2 * tid], a1 = hist[2 * tid + 1];
  s[tid] = a0 + a1;
  __syncthreads();
  for (int off = 1; off < 256; off <<= 1) {
    int t = (tid >= off) ? s[tid - off] : 0;
    __syncthreads();
    s[tid] += t;
    __syncthreads();
  }
  int excl = s[tid] - (a0 + a1);
  loffS[2 * tid]     = excl + 2 * tid;
  loffS[2 * tid + 1] = excl + a0 + 2 * tid + 1;
  __syncthreads();
  cur[2 * tid] = loffS[2 * tid];
  cur[2 * tid + 1] = loffS[2 * tid + 1];
  if (2 * tid < sl)     offs[node0 + 2 * tid]     = cbase + loffS[2 * tid];
  if (2 * tid + 1 < sl) offs[node0 + 2 * tid + 1] = cbase + loffS[2 * tid + 1];
  __syncthreads();
  for (int e = e0 + tid; e < e1; e += 256) {
    int2 u = binned[e];
    int p = atomicAdd(&cur[u.y], 1);
    csr[cbase + p] = u.x;
  }
  for (int i = tid; i < sl; i += 256) {
    int p = atomicAdd(&cur[i], 1);
    csr[cbase + p] = node0 + i;            // self loop
  }
}

// ---- projection of layer-2 attention vectors through W2 -------------------

__global__ __launch_bounds__(128) void k_proj(const float* __restrict__ W2,
                                              const float* __restrict__ a2s,
                                              const float* __restrict__ a2d,
                                              float* __restrict__ w2as, float* __restrict__ w2ad) {
  int t = threadIdx.x;
  if (t < 64) {
    float s = 0.f;
    for (int k = 0; k < 100; ++k) s += W2[t * 100 + k] * a2s[k];
    w2as[t] = s;
  } else {
    int c = t - 64;
    float s = 0.f;
    for (int k = 0; k < 100; ++k) s += W2[c * 100 + k] * a2d[k];
    w2ad[c] = s;
  }
}

// ---- Layer 1 GEMM: h1 = x @ W1 (bf16 out), fused alpha_s/alpha_d ----------

__global__ __launch_bounds__(256) void k_gemm1(const float* __restrict__ x, const float* __restrict__ W,
                                               const float* __restrict__ av_s, const float* __restrict__ av_d,
                                               unsigned short* __restrict__ h1b, float* __restrict__ as1,
                                               float* __restrict__ ad1, int N) {
  __shared__ float xs[64][68];   // [k][row]
  __shared__ float wl[64][64];   // [k][col]
  int tid = threadIdx.x;
  int row0 = blockIdx.x * 64;
  int rg = tid >> 4, cg = tid & 15;
  float acc[4][4] = {};
  for (int kc = 0; kc < 256; kc += 64) {
    int rr = tid >> 4, kq = tid & 15;
#pragma unroll
    for (int p = 0; p < 4; ++p) {
      int r = rr + p * 16;
      int grow = row0 + r;
      float4 v = make_float4(0.f, 0.f, 0.f, 0.f);
      if (grow < N) v = *(const float4*)&x[(size_t)grow * 256 + kc + kq * 4];
      xs[kq * 4 + 0][r] = v.x; xs[kq * 4 + 1][r] = v.y;
      xs[kq * 4 + 2][r] = v.z; xs[kq * 4 + 3][r] = v.w;
      *(float4*)&wl[r][kq * 4] = *(const float4*)&W[(size_t)(kc + r) * 64 + kq * 4];
    }
    __syncthreads();
#pragma unroll 4
    for (int k = 0; k < 64; ++k) {
      float4 xv = *(const float4*)&xs[k][rg * 4];
      float4 wv = *(const float4*)&wl[k][cg * 4];
      float xa[4] = {xv.x, xv.y, xv.z, xv.w};
      float wa[4] = {wv.x, wv.y, wv.z, wv.w};
#pragma unroll
      for (int i = 0; i < 4; ++i)
#pragma unroll
        for (int j = 0; j < 4; ++j) acc[i][j] += xa[i] * wa[j];
    }
    __syncthreads();
  }
  float av[4], bv[4];
#pragma unroll
  for (int j = 0; j < 4; ++j) { av[j] = av_s[cg * 4 + j]; bv[j] = av_d[cg * 4 + j]; }
#pragma unroll
  for (int i = 0; i < 4; ++i) {
    int row = row0 + rg * 4 + i;
    if (row < N) {
      ushort4 o;
      o.x = f2b(acc[i][0]); o.y = f2b(acc[i][1]);
      o.z = f2b(acc[i][2]); o.w = f2b(acc[i][3]);
      *(ushort4*)&h1b[(size_t)row * 64 + cg * 4] = o;
      float ps = acc[i][0] * av[0] + acc[i][1] * av[1] + acc[i][2] * av[2] + acc[i][3] * av[3];
      float pd = acc[i][0] * bv[0] + acc[i][1] * bv[1] + acc[i][2] * bv[2] + acc[i][3] * bv[3];
      ps += __shfl_xor(ps, 1);
      pd += __shfl_xor(pd, 1);
      if ((cg & 1) == 0) {
        as1[row * 8 + (cg >> 1)] = ps;
        ad1[row * 8 + (cg >> 1)] = pd;
      }
    }
  }
}

// ---- Layer 1 aggregate (max-free) + ELU + helu write + as2/ad2 ------------
// Phase B: lanes<cn gather the full as1 row (2xfloat4), compute all 8 head
// weights w=exp(lrelu(.)), write transposed wsm[h][e] (stride 68 -> phase-C
// float4 reads hit 8 groups x 4 banks = 32, conflict-free).
// Phase C: 64 lanes = channels; w read per 4 edges as one ds_read_b128
// (broadcast within 8-lane head group); denom accumulated lane-redundantly.

__global__ __launch_bounds__(256) void k_agg1(const int* __restrict__ csr, const int* __restrict__ offs,
                                              const unsigned short* __restrict__ h1b,
                                              const float* __restrict__ as1, const float* __restrict__ ad1,
                                              const float* __restrict__ b1,
                                              const float* __restrict__ w2as, const float* __restrict__ w2ad,
                                              unsigned short* __restrict__ helu_b,
                                              float* __restrict__ as2, float* __restrict__ ad2, int N) {
  __shared__ float wsm[4][8][68];
  __shared__ int   scs[4][64];
  int tid = threadIdx.x;
  int slot = tid >> 6;
  int node = blockIdx.x * 4 + slot;
  if (node >= N) return;
  int lane = tid & 63;
  int h = lane >> 3;
  int beg = offs[node], end = offs[node + 1];
  int deg = end - beg;
  float4 advlo = *(const float4*)&ad1[node * 8];
  float4 advhi = *(const float4*)&ad1[node * 8 + 4];
  float denom = 0.f, acc = 0.f;
  for (int c0 = 0; c0 < deg; c0 += 64) {
    int cn = min(64, deg - c0);
    if (lane < cn) {
      int sreg = csr[beg + c0 + lane];
      scs[slot][lane] = sreg;
      float4 alo = *(const float4*)&as1[sreg * 8];
      float4 ahi = *(const float4*)&as1[sreg * 8 + 4];
      wsm[slot][0][lane] = __expf(lrelu02(alo.x + advlo.x));
      wsm[slot][1][lane] = __expf(lrelu02(alo.y + advlo.y));
      wsm[slot][2][lane] = __expf(lrelu02(alo.z + advlo.z));
      wsm[slot][3][lane] = __expf(lrelu02(alo.w + advlo.w));
      wsm[slot][4][lane] = __expf(lrelu02(ahi.x + advhi.x));
      wsm[slot][5][lane] = __expf(lrelu02(ahi.y + advhi.y));
      wsm[slot][6][lane] = __expf(lrelu02(ahi.z + advhi.z));
      wsm[slot][7][lane] = __expf(lrelu02(ahi.w + advhi.w));
    }
    int i = 0;
    for (; i + 4 <= cn; i += 4) {
      float4 wq = *(const float4*)&wsm[slot][h][i];
      int4 sq = *(const int4*)&scs[slot][i];
      denom += (wq.x + wq.y) + (wq.z + wq.w);
      acc += wq.x * b2f(h1b[(unsigned)(sq.x * 64) + lane]);
      acc += wq.y * b2f(h1b[(unsigned)(sq.y * 64) + lane]);
      acc += wq.z * b2f(h1b[(unsigned)(sq.z * 64) + lane]);
      acc += wq.w * b2f(h1b[(unsigned)(sq.w * 64) + lane]);
    }
    for (; i < cn; ++i) {
      float wv = wsm[slot][h][i];
      int s = scs[slot][i];
      denom += wv;
      acc += wv * b2f(h1b[(unsigned)(s * 64) + lane]);
    }
  }
  float o = acc / denom + b1[lane];
  o = o > 0.f ? o : expm1f(o);   // ELU(alpha=1)
  helu_b[(size_t)node * 64 + lane] = f2b(o);
  // fused layer-2 alpha: as2 = helu . (W2 @ a_src2), ad2 likewise
  float s2 = o * w2as[lane];
  float d2 = o * w2ad[lane];
#pragma unroll
  for (int off = 32; off; off >>= 1) { s2 += __shfl_xor(s2, off); d2 += __shfl_xor(d2, off); }
  if (lane == 0) { as2[node] = s2; ad2[node] = d2; }
}

// ---- Layer 2 aggregate (max-free) over helu (64 ch, bf16) -----------------

__global__ __launch_bounds__(256) void k_agg2(const int* __restrict__ csr, const int* __restrict__ offs,
                                              const unsigned short* __restrict__ helu_b,
                                              const float* __restrict__ as2, const float* __restrict__ ad2,
                                              float* __restrict__ agg, int N) {
  __shared__ float2 lds2[4][64];
  int tid = threadIdx.x;
  int slot = tid >> 6;
  int node = blockIdx.x * 4 + slot;
  if (node >= N) return;
  int lane = tid & 63;
  int beg = offs[node], end = offs[node + 1];
  int deg = end - beg;
  float adv = ad2[node];
  float denom = 0.f, acc = 0.f;
  for (int c0 = 0; c0 < deg; c0 += 64) {
    int cn = min(64, deg - c0);
    if (lane < cn) {
      int sreg = csr[beg + c0 + lane];
      float w = __expf(lrelu02(as2[sreg] + adv));
      lds2[slot][lane] = make_float2(w, __int_as_float(sreg));
    }
    int i = 0;
    for (; i + 2 <= cn; i += 2) {
      float4 p = *(const float4*)&lds2[slot][i];   // two (w, src) pairs
      denom += p.x + p.z;
      acc += p.x * b2f(helu_b[(unsigned)(__float_as_int(p.y) * 64) + lane]);
      acc += p.z * b2f(helu_b[(unsigned)(__float_as_int(p.w) * 64) + lane]);
    }
    for (; i < cn; ++i) {
      float2 e0 = lds2[slot][i];
      denom += e0.x;
      acc += e0.x * b2f(helu_b[(unsigned)(__float_as_int(e0.y) * 64) + lane]);
    }
  }
  agg[(size_t)node * 64 + lane] = acc / denom;
}

// ---- Final GEMM: out = sigmoid(agg @ W2 + b2)  [N,64]@[64,100] ------------

__global__ __launch_bounds__(256) void k_gemm2b(const float* __restrict__ agg, const float* __restrict__ W2,
                                                const float* __restrict__ b2, float* __restrict__ out, int N) {
  __shared__ float het[64][44];     // [k][row]
  __shared__ float w2l[64 * 100];   // [k][col]
  int tid = threadIdx.x;
  int row0 = blockIdx.x * 40;
  for (int i = tid; i < 6400; i += 256) w2l[i] = W2[i];
  for (int idx = tid; idx < 640; idx += 256) {
    int r = idx >> 4, kq = idx & 15;
    int grow = row0 + r;
    float4 v = make_float4(0.f, 0.f, 0.f, 0.f);
    if (grow < N) v = *(const float4*)&agg[(size_t)grow * 64 + kq * 4];
    het[kq * 4 + 0][r] = v.x; het[kq * 4 + 1][r] = v.y;
    het[kq * 4 + 2][r] = v.z; het[kq * 4 + 3][r] = v.w;
  }
  __syncthreads();
  int rg = tid / 25, cg = tid % 25;
  if (rg >= 10) return;
  float acc[4][4] = {};
#pragma unroll 4
  for (int k = 0; k < 64; ++k) {
    float4 xv = *(const float4*)&het[k][rg * 4];
    float4 wv = *(const float4*)&w2l[k * 100 + cg * 4];
    float xa[4] = {xv.x, xv.y, xv.z, xv.w};
    float wa[4] = {wv.x, wv.y, wv.z, wv.w};
#pragma unroll
    for (int i = 0; i < 4; ++i)
#pragma unroll
      for (int j = 0; j < 4; ++j) acc[i][j] += xa[i] * wa[j];
  }
  float bb[4];
#pragma unroll
  for (int j = 0; j < 4; ++j) bb[j] = b2[cg * 4 + j];
#pragma unroll
  for (int i = 0; i < 4; ++i) {
    int row = row0 + rg * 4 + i;
    if (row < N) {
      float4 o;
      o.x = 1.f / (1.f + __expf(-(acc[i][0] + bb[0])));
      o.y = 1.f / (1.f + __expf(-(acc[i][1] + bb[1])));
      o.z = 1.f / (1.f + __expf(-(acc[i][2] + bb[2])));
      o.w = 1.f / (1.f + __expf(-(acc[i][3] + bb[3])));
      *(float4*)&out[(size_t)row * 100 + cg * 4] = o;
    }
  }
}

// ---------------------------------------------------------------------------

extern "C" void kernel_launch(void* const* d_in, const int* in_sizes, int n_in,
                              void* d_out, int out_size, void* d_ws, size_t ws_size,
                              hipStream_t stream) {
  const float* x    = (const float*)d_in[0];
  const int*   ei   = (const int*)d_in[1];    // harness converts integer inputs to int32
  const float* W1   = (const float*)d_in[2];
  const float* a_s1 = (const float*)d_in[3];
  const float* a_d1 = (const float*)d_in[4];
  const float* b1   = (const float*)d_in[5];
  const float* W2   = (const float*)d_in[6];
  const float* a_s2 = (const float*)d_in[7];
  const float* a_d2 = (const float*)d_in[8];
  const float* b2   = (const float*)d_in[9];
  float* out = (float*)d_out;

  const int N = in_sizes[0] / 256;
  const int E = in_sizes[1] / 2;
  const int K = (N + BNN - 1) >> BSH;       // buckets (<=256 for N<=131072)

  char* w = (char*)d_ws;
  size_t off = 0;
  auto alloc = [&](size_t bytes) -> char* {
    char* p = w + off;
    off = (off + bytes + 255) & ~(size_t)255;
    return p;
  };
  unsigned short* h1b    = (unsigned short*)alloc((size_t)N * 64 * 2);
  unsigned short* helu_b = (unsigned short*)alloc((size_t)N * 64 * 2);
  float* agg  = (float*)alloc((size_t)N * 64 * 4);
  float* as1  = (float*)alloc((size_t)N * 8 * 4);
  float* ad1  = (float*)alloc((size_t)N * 8 * 4);
  float* as2  = (float*)alloc((size_t)N * 4);
  float* ad2  = (float*)alloc((size_t)N * 4);
  float* w2as = (float*)alloc(64 * 4);
  float* w2ad = (float*)alloc(64 * 4);
  int*   offs   = (int*)alloc((size_t)(N + 1) * 4);
  int*   csr    = (int*)alloc((size_t)(E + N) * 4);
  int2*  binned = (int2*)alloc((size_t)E * 8);
  int*   bhist  = (int*)alloc((size_t)(K + 1) * 4);
  int*   bbase  = (int*)alloc((size_t)(K + 1) * 4);
  int*   bcur   = (int*)alloc((size_t)K * 4);
  (void)ws_size; (void)n_in; (void)out_size;

  hipMemsetAsync(bhist, 0, (size_t)K * 4, stream);

  int ebl = (E + 2047) / 2048;
  k_hist<<<ebl, 256, 0, stream>>>(ei, E, bhist);
  k_bscan<<<1, 256, 0, stream>>>(bhist, bbase, bcur, offs, K, E, N);
  k_bin<<<ebl, 256, 0, stream>>>(ei, E, bcur, binned);
  k_bucket<<<K, 256, 0, stream>>>(binned, bbase, offs, csr, N);

  k_proj<<<1, 128, 0, stream>>>(W2, a_s2, a_d2, w2as, w2ad);
  k_gemm1<<<(N + 63) / 64, 256, 0, stream>>>(x, W1, a_s1, a_d1, h1b, as1, ad1, N);
  k_agg1<<<(N + 3) / 4, 256, 0, stream>>>(csr, offs, h1b, as1, ad1, b1, w2as, w2ad,
                                          helu_b, as2, ad2, N);
  k_agg2<<<(N + 3) / 4, 256, 0, stream>>>(csr, offs, helu_b, as2, ad2, agg, N);
  k_gemm2b<<<(N + 39) / 40, 256, 0, stream>>>(agg, W2, b2, out, N);
}

// Round 7
// 279.305 us; speedup vs baseline: 2.6546x; 1.0977x over previous
//
#include <hip/hip_runtime.h>
#include <hip/hip_bf16.h>
#include <cmath>

// ---------------------------------------------------------------------------
// GAT 2-layer forward.
// CSR build via 2-level bucketing. Layer1: fp32 GEMM (bf16 h1 out) -> agg1
// (max-free softmax, vectorized uint2 gather: 4 edge-groups x 16 lanes x 8B)
// fused with helu-bf16 write + as2/ad2 projection. Layer2: same-structure
// aggregate over helu, then GEMM W2 + bias + sigmoid.
// ---------------------------------------------------------------------------

#define BSH 9                 // 512 nodes per bucket; requires N <= 131072
#define BNN (1 << BSH)

__device__ __forceinline__ float lrelu02(float v) { return v > 0.f ? v : 0.2f * v; }

__device__ __forceinline__ float b2f(unsigned short u) {
  union { float f; unsigned int i; } c; c.i = ((unsigned int)u) << 16; return c.f;
}
__device__ __forceinline__ unsigned short f2b(float f) {
  union { float f; unsigned int i; } c; c.f = f;
  unsigned int r = c.i + 0x7FFFu + ((c.i >> 16) & 1u);   // RNE
  return (unsigned short)(r >> 16);
}
__device__ __forceinline__ float lo16(unsigned int u) {
  union { float f; unsigned int i; } c; c.i = u << 16; return c.f;
}
__device__ __forceinline__ float hi16(unsigned int u) {
  union { float f; unsigned int i; } c; c.i = u & 0xFFFF0000u; return c.f;
}

// ---- CSR build: pass A1 — bucket histogram --------------------------------

__global__ __launch_bounds__(256) void k_hist(const int* __restrict__ ei, int E,
                                              int* __restrict__ bhist) {
  __shared__ int lh[256];
  int tid = threadIdx.x;
  lh[tid] = 0;
  __syncthreads();
  int base = blockIdx.x * 2048;
#pragma unroll
  for (int j = 0; j < 8; ++j) {
    int e = base + j * 256 + tid;
    if (e < E) atomicAdd(&lh[ei[E + e] >> BSH], 1);
  }
  __syncthreads();
  if (lh[tid]) atomicAdd(&bhist[tid], lh[tid]);
}

// ---- pass A2 — scan bucket counts (single block) --------------------------

__global__ __launch_bounds__(256) void k_bscan(const int* __restrict__ bhist,
                                               int* __restrict__ bbase, int* __restrict__ bcur,
                                               int* __restrict__ offs, int K, int E, int N) {
  __shared__ int s[256];
  int tid = threadIdx.x;
  int v = (tid < K) ? bhist[tid] : 0;
  s[tid] = v;
  __syncthreads();
  for (int off = 1; off < 256; off <<= 1) {
    int t = (tid >= off) ? s[tid - off] : 0;
    __syncthreads();
    s[tid] += t;
    __syncthreads();
  }
  int excl = s[tid] - v;
  if (tid < K) { bbase[tid] = excl; bcur[tid] = excl; }
  if (tid == 255) bbase[K] = s[255];    // = E
  if (tid == 0) offs[N] = E + N;
}

// ---- pass A3 — bin edges into buckets as (src, dst_local) -----------------

__global__ __launch_bounds__(256) void k_bin(const int* __restrict__ ei, int E,
                                             int* __restrict__ bcur, int2* __restrict__ binned) {
  __shared__ int lh[256];
  __shared__ int lbase[256];
  int tid = threadIdx.x;
  lh[tid] = 0;
  __syncthreads();
  int base = blockIdx.x * 2048;
  int bj[8], rk[8], sj[8], dl[8];
#pragma unroll
  for (int j = 0; j < 8; ++j) {
    int e = base + j * 256 + tid;
    bj[j] = -1;
    if (e < E) {
      sj[j] = ei[e];
      int d = ei[E + e];
      bj[j] = d >> BSH;
      dl[j] = d & (BNN - 1);
      rk[j] = atomicAdd(&lh[bj[j]], 1);
    }
  }
  __syncthreads();
  if (lh[tid]) lbase[tid] = atomicAdd(&bcur[tid], lh[tid]);
  __syncthreads();
#pragma unroll
  for (int j = 0; j < 8; ++j)
    if (bj[j] >= 0) binned[lbase[bj[j]] + rk[j]] = make_int2(sj[j], dl[j]);
}

// ---- pass B — per-bucket CSR fill (one block per bucket) ------------------

__global__ __launch_bounds__(256) void k_bucket(const int2* __restrict__ binned,
                                                const int* __restrict__ bbase,
                                                int* __restrict__ offs, int* __restrict__ csr,
                                                int N) {
  __shared__ int hist[BNN], loffS[BNN], cur[BNN];
  __shared__ int s[256];
  int tid = threadIdx.x;
  int b = blockIdx.x;
  int node0 = b << BSH;
  int sl = min(BNN, N - node0);
  int e0 = bbase[b], e1 = bbase[b + 1];
  int cbase = e0 + min(node0, N);          // csr base incl. upstream self-loops
  hist[tid] = 0; hist[tid + 256] = 0;
  __syncthreads();
  for (int e = e0 + tid; e < e1; e += 256) atomicAdd(&hist[binned[e].y], 1);
  __syncthreads();
  int a0 = hist[2 * tid], a1 = hist[2 * tid + 1];
  s[tid] = a0 + a1;
  __syncthreads();
  for (int off = 1; off < 256; off <<= 1) {
    int t = (tid >= off) ? s[tid - off] : 0;
    __syncthreads();
    s[tid] += t;
    __syncthreads();
  }
  int excl = s[tid] - (a0 + a1);
  loffS[2 * tid]     = excl + 2 * tid;
  loffS[2 * tid + 1] = excl + a0 + 2 * tid + 1;
  __syncthreads();
  cur[2 * tid] = loffS[2 * tid];
  cur[2 * tid + 1] = loffS[2 * tid + 1];
  if (2 * tid < sl)     offs[node0 + 2 * tid]     = cbase + loffS[2 * tid];
  if (2 * tid + 1 < sl) offs[node0 + 2 * tid + 1] = cbase + loffS[2 * tid + 1];
  __syncthreads();
  for (int e = e0 + tid; e < e1; e += 256) {
    int2 u = binned[e];
    int p = atomicAdd(&cur[u.y], 1);
    csr[cbase + p] = u.x;
  }
  for (int i = tid; i < sl; i += 256) {
    int p = atomicAdd(&cur[i], 1);
    csr[cbase + p] = node0 + i;            // self loop
  }
}

// ---- projection of layer-2 attention vectors through W2 -------------------

__global__ __launch_bounds__(128) void k_proj(const float* __restrict__ W2,
                                              const float* __restrict__ a2s,
                                              const float* __restrict__ a2d,
                                              float* __restrict__ w2as, float* __restrict__ w2ad) {
  int t = threadIdx.x;
  if (t < 64) {
    float s = 0.f;
    for (int k = 0; k < 100; ++k) s += W2[t * 100 + k] * a2s[k];
    w2as[t] = s;
  } else {
    int c = t - 64;
    float s = 0.f;
    for (int k = 0; k < 100; ++k) s += W2[c * 100 + k] * a2d[k];
    w2ad[c] = s;
  }
}

// ---- Layer 1 GEMM: h1 = x @ W1 (bf16 out), fused alpha_s/alpha_d ----------

__global__ __launch_bounds__(256) void k_gemm1(const float* __restrict__ x, const float* __restrict__ W,
                                               const float* __restrict__ av_s, const float* __restrict__ av_d,
                                               unsigned short* __restrict__ h1b, float* __restrict__ as1,
                                               float* __restrict__ ad1, int N) {
  __shared__ float xs[64][68];   // [k][row]
  __shared__ float wl[64][64];   // [k][col]
  int tid = threadIdx.x;
  int row0 = blockIdx.x * 64;
  int rg = tid >> 4, cg = tid & 15;
  float acc[4][4] = {};
  for (int kc = 0; kc < 256; kc += 64) {
    int rr = tid >> 4, kq = tid & 15;
#pragma unroll
    for (int p = 0; p < 4; ++p) {
      int r = rr + p * 16;
      int grow = row0 + r;
      float4 v = make_float4(0.f, 0.f, 0.f, 0.f);
      if (grow < N) v = *(const float4*)&x[(size_t)grow * 256 + kc + kq * 4];
      xs[kq * 4 + 0][r] = v.x; xs[kq * 4 + 1][r] = v.y;
      xs[kq * 4 + 2][r] = v.z; xs[kq * 4 + 3][r] = v.w;
      *(float4*)&wl[r][kq * 4] = *(const float4*)&W[(size_t)(kc + r) * 64 + kq * 4];
    }
    __syncthreads();
#pragma unroll 4
    for (int k = 0; k < 64; ++k) {
      float4 xv = *(const float4*)&xs[k][rg * 4];
      float4 wv = *(const float4*)&wl[k][cg * 4];
      float xa[4] = {xv.x, xv.y, xv.z, xv.w};
      float wa[4] = {wv.x, wv.y, wv.z, wv.w};
#pragma unroll
      for (int i = 0; i < 4; ++i)
#pragma unroll
        for (int j = 0; j < 4; ++j) acc[i][j] += xa[i] * wa[j];
    }
    __syncthreads();
  }
  float av[4], bv[4];
#pragma unroll
  for (int j = 0; j < 4; ++j) { av[j] = av_s[cg * 4 + j]; bv[j] = av_d[cg * 4 + j]; }
#pragma unroll
  for (int i = 0; i < 4; ++i) {
    int row = row0 + rg * 4 + i;
    if (row < N) {
      ushort4 o;
      o.x = f2b(acc[i][0]); o.y = f2b(acc[i][1]);
      o.z = f2b(acc[i][2]); o.w = f2b(acc[i][3]);
      *(ushort4*)&h1b[(size_t)row * 64 + cg * 4] = o;
      float ps = acc[i][0] * av[0] + acc[i][1] * av[1] + acc[i][2] * av[2] + acc[i][3] * av[3];
      float pd = acc[i][0] * bv[0] + acc[i][1] * bv[1] + acc[i][2] * bv[2] + acc[i][3] * bv[3];
      ps += __shfl_xor(ps, 1);
      pd += __shfl_xor(pd, 1);
      if ((cg & 1) == 0) {
        as1[row * 8 + (cg >> 1)] = ps;
        ad1[row * 8 + (cg >> 1)] = pd;
      }
    }
  }
}

// ---- Layer 1 aggregate (max-free, vectorized gather) ----------------------
// Wave = 4 edge-groups (g=lane>>4) x 16 lanes (q=lane&15). Lane handles
// channels 4q..4q+3 (head q>>1) of edge i+g: one uint2 load = 8B = 4 bf16;
// 16 lanes cover the full 128B row. Cross-group combine: shfl_xor(16|32).

__global__ __launch_bounds__(256) void k_agg1(const int* __restrict__ csr, const int* __restrict__ offs,
                                              const unsigned short* __restrict__ h1b,
                                              const float* __restrict__ as1, const float* __restrict__ ad1,
                                              const float* __restrict__ b1,
                                              const float* __restrict__ w2as, const float* __restrict__ w2ad,
                                              unsigned short* __restrict__ helu_b,
                                              float* __restrict__ as2, float* __restrict__ ad2, int N) {
  __shared__ float wsm[4][8][68];
  __shared__ int   scs[4][64];
  int tid = threadIdx.x;
  int slot = tid >> 6;
  int node = blockIdx.x * 4 + slot;
  if (node >= N) return;
  int lane = tid & 63;
  int g = lane >> 4, q = lane & 15, h = q >> 1;
  int beg = offs[node], end = offs[node + 1];
  int deg = end - beg;
  float4 advlo = *(const float4*)&ad1[node * 8];
  float4 advhi = *(const float4*)&ad1[node * 8 + 4];
  float denom = 0.f;
  float4 acc = make_float4(0.f, 0.f, 0.f, 0.f);
  for (int c0 = 0; c0 < deg; c0 += 64) {
    int cn = min(64, deg - c0);
    // phase B: lane e<cn computes all 8 head weights for its edge
    if (lane < cn) {
      int sreg = csr[beg + c0 + lane];
      scs[slot][lane] = sreg;
      float4 alo = *(const float4*)&as1[sreg * 8];
      float4 ahi = *(const float4*)&as1[sreg * 8 + 4];
      wsm[slot][0][lane] = __expf(lrelu02(alo.x + advlo.x));
      wsm[slot][1][lane] = __expf(lrelu02(alo.y + advlo.y));
      wsm[slot][2][lane] = __expf(lrelu02(alo.z + advlo.z));
      wsm[slot][3][lane] = __expf(lrelu02(alo.w + advlo.w));
      wsm[slot][4][lane] = __expf(lrelu02(ahi.x + advhi.x));
      wsm[slot][5][lane] = __expf(lrelu02(ahi.y + advhi.y));
      wsm[slot][6][lane] = __expf(lrelu02(ahi.z + advhi.z));
      wsm[slot][7][lane] = __expf(lrelu02(ahi.w + advhi.w));
    }
    // phase C: group g takes edges i+g; lane loads its 4 channels (uint2)
    int i = 0;
    for (; i + 8 <= cn; i += 8) {
      int e0 = i + g, e1 = i + 4 + g;
      int s0 = scs[slot][e0], s1 = scs[slot][e1];
      float w0 = wsm[slot][h][e0], w1 = wsm[slot][h][e1];
      uint2 p0 = *(const uint2*)&h1b[(unsigned)s0 * 64 + q * 4];
      uint2 p1 = *(const uint2*)&h1b[(unsigned)s1 * 64 + q * 4];
      denom += w0 + w1;
      acc.x += w0 * lo16(p0.x); acc.y += w0 * hi16(p0.x);
      acc.z += w0 * lo16(p0.y); acc.w += w0 * hi16(p0.y);
      acc.x += w1 * lo16(p1.x); acc.y += w1 * hi16(p1.x);
      acc.z += w1 * lo16(p1.y); acc.w += w1 * hi16(p1.y);
    }
    for (; i < cn; i += 4) {
      int e = i + g;
      if (e < cn) {
        int s = scs[slot][e];
        float w = wsm[slot][h][e];
        uint2 p = *(const uint2*)&h1b[(unsigned)s * 64 + q * 4];
        denom += w;
        acc.x += w * lo16(p.x); acc.y += w * hi16(p.x);
        acc.z += w * lo16(p.y); acc.w += w * hi16(p.y);
      }
    }
  }
  // combine the 4 edge-groups (every lane ends with the full sums)
#pragma unroll
  for (int off = 16; off <= 32; off <<= 1) {
    acc.x += __shfl_xor(acc.x, off);
    acc.y += __shfl_xor(acc.y, off);
    acc.z += __shfl_xor(acc.z, off);
    acc.w += __shfl_xor(acc.w, off);
    denom += __shfl_xor(denom, off);
  }
  float rd = 1.f / denom;
  float4 bq = *(const float4*)&b1[q * 4];
  float o0 = acc.x * rd + bq.x;
  float o1 = acc.y * rd + bq.y;
  float o2 = acc.z * rd + bq.z;
  float o3 = acc.w * rd + bq.w;
  o0 = o0 > 0.f ? o0 : expm1f(o0);
  o1 = o1 > 0.f ? o1 : expm1f(o1);
  o2 = o2 > 0.f ? o2 : expm1f(o2);
  o3 = o3 > 0.f ? o3 : expm1f(o3);
  if (g == 0) {
    ushort4 ob; ob.x = f2b(o0); ob.y = f2b(o1); ob.z = f2b(o2); ob.w = f2b(o3);
    *(ushort4*)&helu_b[(size_t)node * 64 + q * 4] = ob;
  }
  // fused layer-2 alpha (lanes 16-63 hold identical copies; xor<16 reduces)
  float4 was = *(const float4*)&w2as[q * 4];
  float4 wad = *(const float4*)&w2ad[q * 4];
  float s2 = o0 * was.x + o1 * was.y + o2 * was.z + o3 * was.w;
  float d2 = o0 * wad.x + o1 * wad.y + o2 * wad.z + o3 * wad.w;
#pragma unroll
  for (int off = 1; off < 16; off <<= 1) {
    s2 += __shfl_xor(s2, off);
    d2 += __shfl_xor(d2, off);
  }
  if (lane == 0) { as2[node] = s2; ad2[node] = d2; }
}

// ---- Layer 2 aggregate (max-free, vectorized gather) over helu ------------

__global__ __launch_bounds__(256) void k_agg2(const int* __restrict__ csr, const int* __restrict__ offs,
                                              const unsigned short* __restrict__ helu_b,
                                              const float* __restrict__ as2, const float* __restrict__ ad2,
                                              float* __restrict__ agg, int N) {
  __shared__ float wls[4][68];
  __shared__ int   scs[4][64];
  int tid = threadIdx.x;
  int slot = tid >> 6;
  int node = blockIdx.x * 4 + slot;
  if (node >= N) return;
  int lane = tid & 63;
  int g = lane >> 4, q = lane & 15;
  int beg = offs[node], end = offs[node + 1];
  int deg = end - beg;
  float adv = ad2[node];
  float denom = 0.f;
  float4 acc = make_float4(0.f, 0.f, 0.f, 0.f);
  for (int c0 = 0; c0 < deg; c0 += 64) {
    int cn = min(64, deg - c0);
    if (lane < cn) {
      int sreg = csr[beg + c0 + lane];
      scs[slot][lane] = sreg;
      wls[slot][lane] = __expf(lrelu02(as2[sreg] + adv));
    }
    int i = 0;
    for (; i + 8 <= cn; i += 8) {
      int e0 = i + g, e1 = i + 4 + g;
      int s0 = scs[slot][e0], s1 = scs[slot][e1];
      float w0 = wls[slot][e0], w1 = wls[slot][e1];
      uint2 p0 = *(const uint2*)&helu_b[(unsigned)s0 * 64 + q * 4];
      uint2 p1 = *(const uint2*)&helu_b[(unsigned)s1 * 64 + q * 4];
      denom += w0 + w1;
      acc.x += w0 * lo16(p0.x); acc.y += w0 * hi16(p0.x);
      acc.z += w0 * lo16(p0.y); acc.w += w0 * hi16(p0.y);
      acc.x += w1 * lo16(p1.x); acc.y += w1 * hi16(p1.x);
      acc.z += w1 * lo16(p1.y); acc.w += w1 * hi16(p1.y);
    }
    for (; i < cn; i += 4) {
      int e = i + g;
      if (e < cn) {
        int s = scs[slot][e];
        float w = wls[slot][e];
        uint2 p = *(const uint2*)&helu_b[(unsigned)s * 64 + q * 4];
        denom += w;
        acc.x += w * lo16(p.x); acc.y += w * hi16(p.x);
        acc.z += w * lo16(p.y); acc.w += w * hi16(p.y);
      }
    }
  }
#pragma unroll
  for (int off = 16; off <= 32; off <<= 1) {
    acc.x += __shfl_xor(acc.x, off);
    acc.y += __shfl_xor(acc.y, off);
    acc.z += __shfl_xor(acc.z, off);
    acc.w += __shfl_xor(acc.w, off);
    denom += __shfl_xor(denom, off);
  }
  if (g == 0) {
    float rd = 1.f / denom;
    float4 o; o.x = acc.x * rd; o.y = acc.y * rd; o.z = acc.z * rd; o.w = acc.w * rd;
    *(float4*)&agg[(size_t)node * 64 + q * 4] = o;
  }
}

// ---- Final GEMM: out = sigmoid(agg @ W2 + b2)  [N,64]@[64,100] ------------

__global__ __launch_bounds__(256) void k_gemm2b(const float* __restrict__ agg, const float* __restrict__ W2,
                                                const float* __restrict__ b2, float* __restrict__ out, int N) {
  __shared__ float het[64][44];     // [k][row]
  __shared__ float w2l[64 * 100];   // [k][col]
  int tid = threadIdx.x;
  int row0 = blockIdx.x * 40;
  for (int i = tid; i < 6400; i += 256) w2l[i] = W2[i];
  for (int idx = tid; idx < 640; idx += 256) {
    int r = idx >> 4, kq = idx & 15;
    int grow = row0 + r;
    float4 v = make_float4(0.f, 0.f, 0.f, 0.f);
    if (grow < N) v = *(const float4*)&agg[(size_t)grow * 64 + kq * 4];
    het[kq * 4 + 0][r] = v.x; het[kq * 4 + 1][r] = v.y;
    het[kq * 4 + 2][r] = v.z; het[kq * 4 + 3][r] = v.w;
  }
  __syncthreads();
  int rg = tid / 25, cg = tid % 25;
  if (rg >= 10) return;
  float acc[4][4] = {};
#pragma unroll 4
  for (int k = 0; k < 64; ++k) {
    float4 xv = *(const float4*)&het[k][rg * 4];
    float4 wv = *(const float4*)&w2l[k * 100 + cg * 4];
    float xa[4] = {xv.x, xv.y, xv.z, xv.w};
    float wa[4] = {wv.x, wv.y, wv.z, wv.w};
#pragma unroll
    for (int i = 0; i < 4; ++i)
#pragma unroll
      for (int j = 0; j < 4; ++j) acc[i][j] += xa[i] * wa[j];
  }
  float bb[4];
#pragma unroll
  for (int j = 0; j < 4; ++j) bb[j] = b2[cg * 4 + j];
#pragma unroll
  for (int i = 0; i < 4; ++i) {
    int row = row0 + rg * 4 + i;
    if (row < N) {
      float4 o;
      o.x = 1.f / (1.f + __expf(-(acc[i][0] + bb[0])));
      o.y = 1.f / (1.f + __expf(-(acc[i][1] + bb[1])));
      o.z = 1.f / (1.f + __expf(-(acc[i][2] + bb[2])));
      o.w = 1.f / (1.f + __expf(-(acc[i][3] + bb[3])));
      *(float4*)&out[(size_t)row * 100 + cg * 4] = o;
    }
  }
}

// ---------------------------------------------------------------------------

extern "C" void kernel_launch(void* const* d_in, const int* in_sizes, int n_in,
                              void* d_out, int out_size, void* d_ws, size_t ws_size,
                              hipStream_t stream) {
  const float* x    = (const float*)d_in[0];
  const int*   ei   = (const int*)d_in[1];    // harness converts integer inputs to int32
  const float* W1   = (const float*)d_in[2];
  const float* a_s1 = (const float*)d_in[3];
  const float* a_d1 = (const float*)d_in[4];
  const float* b1   = (const float*)d_in[5];
  const float* W2   = (const float*)d_in[6];
  const float* a_s2 = (const float*)d_in[7];
  const float* a_d2 = (const float*)d_in[8];
  const float* b2   = (const float*)d_in[9];
  float* out = (float*)d_out;

  const int N = in_sizes[0] / 256;
  const int E = in_sizes[1] / 2;
  const int K = (N + BNN - 1) >> BSH;       // buckets (<=256 for N<=131072)

  char* w = (char*)d_ws;
  size_t off = 0;
  auto alloc = [&](size_t bytes) -> char* {
    char* p = w + off;
    off = (off + bytes + 255) & ~(size_t)255;
    return p;
  };
  unsigned short* h1b    = (unsigned short*)alloc((size_t)N * 64 * 2);
  unsigned short* helu_b = (unsigned short*)alloc((size_t)N * 64 * 2);
  float* agg  = (float*)alloc((size_t)N * 64 * 4);
  float* as1  = (float*)alloc((size_t)N * 8 * 4);
  float* ad1  = (float*)alloc((size_t)N * 8 * 4);
  float* as2  = (float*)alloc((size_t)N * 4);
  float* ad2  = (float*)alloc((size_t)N * 4);
  float* w2as = (float*)alloc(64 * 4);
  float* w2ad = (float*)alloc(64 * 4);
  int*   offs   = (int*)alloc((size_t)(N + 1) * 4);
  int*   csr    = (int*)alloc((size_t)(E + N) * 4);
  int2*  binned = (int2*)alloc((size_t)E * 8);
  int*   bhist  = (int*)alloc((size_t)(K + 1) * 4);
  int*   bbase  = (int*)alloc((size_t)(K + 1) * 4);
  int*   bcur   = (int*)alloc((size_t)K * 4);
  (void)ws_size; (void)n_in; (void)out_size;

  hipMemsetAsync(bhist, 0, (size_t)K * 4, stream);

  int ebl = (E + 2047) / 2048;
  k_hist<<<ebl, 256, 0, stream>>>(ei, E, bhist);
  k_bscan<<<1, 256, 0, stream>>>(bhist, bbase, bcur, offs, K, E, N);
  k_bin<<<ebl, 256, 0, stream>>>(ei, E, bcur, binned);
  k_bucket<<<K, 256, 0, stream>>>(binned, bbase, offs, csr, N);

  k_proj<<<1, 128, 0, stream>>>(W2, a_s2, a_d2, w2as, w2ad);
  k_gemm1<<<(N + 63) / 64, 256, 0, stream>>>(x, W1, a_s1, a_d1, h1b, as1, ad1, N);
  k_agg1<<<(N + 3) / 4, 256, 0, stream>>>(csr, offs, h1b, as1, ad1, b1, w2as, w2ad,
                                          helu_b, as2, ad2, N);
  k_agg2<<<(N + 3) / 4, 256, 0, stream>>>(csr, offs, helu_b, as2, ad2, agg, N);
  k_gemm2b<<<(N + 39) / 40, 256, 0, stream>>>(agg, W2, b2, out, N);
}

// Round 8
// 263.776 us; speedup vs baseline: 2.8109x; 1.0589x over previous
//
#include <hip/hip_runtime.h>
#include <hip/hip_bf16.h>
#include <cmath>

// ---------------------------------------------------------------------------
// GAT 2-layer forward.
// CSR build via 2-level bucketing. Layer1: bf16 MFMA GEMM (16x16x32) with
// fused alpha epilogue -> agg1 (max-free softmax, uint4 gather: 8 groups x
// 8 lanes x 16B) fused with helu-bf16 + as2/ad2 projection. Layer2: same
// aggregate over helu, then fp32 GEMM W2 + bias + sigmoid.
// ---------------------------------------------------------------------------

#define BSH 9                 // 512 nodes per bucket; requires N <= 131072
#define BNN (1 << BSH)

typedef __attribute__((ext_vector_type(8))) short short8v;
typedef __attribute__((ext_vector_type(4))) float f32x4;

__device__ __forceinline__ float lrelu02(float v) { return v > 0.f ? v : 0.2f * v; }

__device__ __forceinline__ unsigned short f2b(float f) {
  union { float f; unsigned int i; } c; c.f = f;
  unsigned int r = c.i + 0x7FFFu + ((c.i >> 16) & 1u);   // RNE
  return (unsigned short)(r >> 16);
}
__device__ __forceinline__ float lo16(unsigned int u) {
  union { float f; unsigned int i; } c; c.i = u << 16; return c.f;
}
__device__ __forceinline__ float hi16(unsigned int u) {
  union { float f; unsigned int i; } c; c.i = u & 0xFFFF0000u; return c.f;
}

// ---- CSR build: pass A1 — bucket histogram --------------------------------

__global__ __launch_bounds__(256) void k_hist(const int* __restrict__ ei, int E,
                                              int* __restrict__ bhist) {
  __shared__ int lh[256];
  int tid = threadIdx.x;
  lh[tid] = 0;
  __syncthreads();
  int base = blockIdx.x * 2048;
#pragma unroll
  for (int j = 0; j < 8; ++j) {
    int e = base + j * 256 + tid;
    if (e < E) atomicAdd(&lh[ei[E + e] >> BSH], 1);
  }
  __syncthreads();
  if (lh[tid]) atomicAdd(&bhist[tid], lh[tid]);
}

// ---- pass A2 — scan bucket counts (single block) --------------------------

__global__ __launch_bounds__(256) void k_bscan(const int* __restrict__ bhist,
                                               int* __restrict__ bbase, int* __restrict__ bcur,
                                               int* __restrict__ offs, int K, int E, int N) {
  __shared__ int s[256];
  int tid = threadIdx.x;
  int v = (tid < K) ? bhist[tid] : 0;
  s[tid] = v;
  __syncthreads();
  for (int off = 1; off < 256; off <<= 1) {
    int t = (tid >= off) ? s[tid - off] : 0;
    __syncthreads();
    s[tid] += t;
    __syncthreads();
  }
  int excl = s[tid] - v;
  if (tid < K) { bbase[tid] = excl; bcur[tid] = excl; }
  if (tid == 255) bbase[K] = s[255];    // = E
  if (tid == 0) offs[N] = E + N;
}

// ---- pass A3 — bin edges into buckets as (src, dst_local) -----------------

__global__ __launch_bounds__(256) void k_bin(const int* __restrict__ ei, int E,
                                             int* __restrict__ bcur, int2* __restrict__ binned) {
  __shared__ int lh[256];
  __shared__ int lbase[256];
  int tid = threadIdx.x;
  lh[tid] = 0;
  __syncthreads();
  int base = blockIdx.x * 2048;
  int bj[8], rk[8], sj[8], dl[8];
#pragma unroll
  for (int j = 0; j < 8; ++j) {
    int e = base + j * 256 + tid;
    bj[j] = -1;
    if (e < E) {
      sj[j] = ei[e];
      int d = ei[E + e];
      bj[j] = d >> BSH;
      dl[j] = d & (BNN - 1);
      rk[j] = atomicAdd(&lh[bj[j]], 1);
    }
  }
  __syncthreads();
  if (lh[tid]) lbase[tid] = atomicAdd(&bcur[tid], lh[tid]);
  __syncthreads();
#pragma unroll
  for (int j = 0; j < 8; ++j)
    if (bj[j] >= 0) binned[lbase[bj[j]] + rk[j]] = make_int2(sj[j], dl[j]);
}

// ---- pass B — per-bucket CSR fill (one block per bucket) ------------------

__global__ __launch_bounds__(256) void k_bucket(const int2* __restrict__ binned,
                                                const int* __restrict__ bbase,
                                                int* __restrict__ offs, int* __restrict__ csr,
                                                int N) {
  __shared__ int hist[BNN], loffS[BNN], cur[BNN];
  __shared__ int s[256];
  int tid = threadIdx.x;
  int b = blockIdx.x;
  int node0 = b << BSH;
  int sl = min(BNN, N - node0);
  int e0 = bbase[b], e1 = bbase[b + 1];
  int cbase = e0 + min(node0, N);          // csr base incl. upstream self-loops
  hist[tid] = 0; hist[tid + 256] = 0;
  __syncthreads();
  for (int e = e0 + tid; e < e1; e += 256) atomicAdd(&hist[binned[e].y], 1);
  __syncthreads();
  int a0 = hist[2 * tid], a1 = hist[2 * tid + 1];
  s[tid] = a0 + a1;
  __syncthreads();
  for (int off = 1; off < 256; off <<= 1) {
    int t = (tid >= off) ? s[tid - off] : 0;
    __syncthreads();
    s[tid] += t;
    __syncthreads();
  }
  int excl = s[tid] - (a0 + a1);
  loffS[2 * tid]     = excl + 2 * tid;
  loffS[2 * tid + 1] = excl + a0 + 2 * tid + 1;
  __syncthreads();
  cur[2 * tid] = loffS[2 * tid];
  cur[2 * tid + 1] = loffS[2 * tid + 1];
  if (2 * tid < sl)     offs[node0 + 2 * tid]     = cbase + loffS[2 * tid];
  if (2 * tid + 1 < sl) offs[node0 + 2 * tid + 1] = cbase + loffS[2 * tid + 1];
  __syncthreads();
  for (int e = e0 + tid; e < e1; e += 256) {
    int2 u = binned[e];
    int p = atomicAdd(&cur[u.y], 1);
    csr[cbase + p] = u.x;
  }
  for (int i = tid; i < sl; i += 256) {
    int p = atomicAdd(&cur[i], 1);
    csr[cbase + p] = node0 + i;            // self loop
  }
}

// ---- prep: W1 transposed to bf16 [64 cols][256 k] -------------------------

__global__ __launch_bounds__(256) void k_prep(const float* __restrict__ W1,
                                              unsigned short* __restrict__ w1t) {
  int idx = blockIdx.x * 256 + threadIdx.x;   // 0..4095
#pragma unroll
  for (int j = 0; j < 4; ++j) {
    int e = idx * 4 + j;                      // flat w1t index = col*256 + k
    int col = e >> 8, k = e & 255;
    w1t[e] = f2b(W1[k * 64 + col]);
  }
}

// ---- projection of layer-2 attention vectors through W2 -------------------

__global__ __launch_bounds__(128) void k_proj(const float* __restrict__ W2,
                                              const float* __restrict__ a2s,
                                              const float* __restrict__ a2d,
                                              float* __restrict__ w2as, float* __restrict__ w2ad) {
  int t = threadIdx.x;
  if (t < 64) {
    float s = 0.f;
    for (int k = 0; k < 100; ++k) s += W2[t * 100 + k] * a2s[k];
    w2as[t] = s;
  } else {
    int c = t - 64;
    float s = 0.f;
    for (int k = 0; k < 100; ++k) s += W2[c * 100 + k] * a2d[k];
    w2ad[c] = s;
  }
}

// ---- Layer 1 GEMM via MFMA: h1 = x @ W1 (bf16 in/out, fp32 acc) -----------
// Block: 64 rows x 64 cols, 4 waves (wave w: rows 16w..16w+15, all cols).
// LDS: x bf16 [64][264], W1^T bf16 [64 cols][264]. 8 K-steps of 32.
// A frag: lane reads x[16w + (l&15)][(l>>4)*8 + 32ks ..+7]  (ds_read_b128)
// B frag: lane reads w1t[16f + (l&15)][same k]               (ds_read_b128)
// D: col = l&15 (+16f), row = 16w + (l>>4)*4 + reg.

__global__ __launch_bounds__(256) void k_gemm1(const float* __restrict__ x,
                                               const unsigned short* __restrict__ w1t,
                                               const float* __restrict__ av_s, const float* __restrict__ av_d,
                                               unsigned short* __restrict__ h1b, float* __restrict__ as1,
                                               float* __restrict__ ad1, int N) {
  __shared__ unsigned short xs[64 * 264];
  __shared__ unsigned short ws[64 * 264];
  int tid = threadIdx.x;
  int row0 = blockIdx.x * 64;
#pragma unroll
  for (int it = 0; it < 8; ++it) {
    int slot = tid + it * 256;              // 0..2047
    int row = slot >> 5, kg = slot & 31;    // k-base = kg*8
    int grow = row0 + row;
    uint4 pk = make_uint4(0u, 0u, 0u, 0u);
    if (grow < N) {
      const float* px = &x[(size_t)grow * 256 + kg * 8];
      float4 v0 = *(const float4*)px;
      float4 v1 = *(const float4*)(px + 4);
      pk.x = f2b(v0.x) | ((unsigned)f2b(v0.y) << 16);
      pk.y = f2b(v0.z) | ((unsigned)f2b(v0.w) << 16);
      pk.z = f2b(v1.x) | ((unsigned)f2b(v1.y) << 16);
      pk.w = f2b(v1.z) | ((unsigned)f2b(v1.w) << 16);
    }
    *(uint4*)&xs[row * 264 + kg * 8] = pk;
    *(uint4*)&ws[row * 264 + kg * 8] = *(const uint4*)&w1t[row * 256 + kg * 8];
  }
  __syncthreads();
  int w = tid >> 6, lane = tid & 63;
  int r16 = lane & 15, kg4 = lane >> 4;
  f32x4 acc[4];
#pragma unroll
  for (int f = 0; f < 4; ++f) acc[f] = (f32x4){0.f, 0.f, 0.f, 0.f};
  const unsigned short* xrow = &xs[(16 * w + r16) * 264 + kg4 * 8];
#pragma unroll
  for (int ks = 0; ks < 8; ++ks) {
    short8v a = *(const short8v*)(xrow + ks * 32);
#pragma unroll
    for (int f = 0; f < 4; ++f) {
      short8v b = *(const short8v*)&ws[(16 * f + r16) * 264 + kg4 * 8 + ks * 32];
      acc[f] = __builtin_amdgcn_mfma_f32_16x16x32_bf16(a, b, acc[f], 0, 0, 0);
    }
  }
  // epilogue: h1 bf16 + per-head alpha reduce (heads 2f + (r16>>3))
  float avv[4], bvv[4];
#pragma unroll
  for (int f = 0; f < 4; ++f) { avv[f] = av_s[16 * f + r16]; bvv[f] = av_d[16 * f + r16]; }
  int rbase = row0 + 16 * w + kg4 * 4;
#pragma unroll
  for (int reg = 0; reg < 4; ++reg) {
    int row = rbase + reg;
    bool ok = row < N;
    if (ok) {
#pragma unroll
      for (int f = 0; f < 4; ++f)
        h1b[(size_t)row * 64 + 16 * f + r16] = f2b(acc[f][reg]);
    }
    float ts[4], td[4];
#pragma unroll
    for (int f = 0; f < 4; ++f) { ts[f] = acc[f][reg] * avv[f]; td[f] = acc[f][reg] * bvv[f]; }
#pragma unroll
    for (int off = 1; off <= 4; off <<= 1) {
#pragma unroll
      for (int f = 0; f < 4; ++f) {
        ts[f] += __shfl_xor(ts[f], off);
        td[f] += __shfl_xor(td[f], off);
      }
    }
    if (ok && (r16 & 7) == 0) {
      int bsel = r16 >> 3;
#pragma unroll
      for (int f = 0; f < 4; ++f) {
        as1[row * 8 + 2 * f + bsel] = ts[f];
        ad1[row * 8 + 2 * f + bsel] = td[f];
      }
    }
  }
}

// ---- Layer 1 aggregate (max-free, uint4 gather) ---------------------------
// Wave = 8 edge-groups (g=lane>>3) x 8 lanes (q=lane&7). Lane = head q,
// channels 8q..8q+7 of edge i+g: one uint4 load = 16B = 8 bf16; 8 lanes
// cover the 128B row. Cross-group combine: shfl_xor(8|16|32).

__global__ __launch_bounds__(256) void k_agg1(const int* __restrict__ csr, const int* __restrict__ offs,
                                              const unsigned short* __restrict__ h1b,
                                              const float* __restrict__ as1, const float* __restrict__ ad1,
                                              const float* __restrict__ b1,
                                              const float* __restrict__ w2as, const float* __restrict__ w2ad,
                                              unsigned short* __restrict__ helu_b,
                                              float* __restrict__ as2, float* __restrict__ ad2, int N) {
  __shared__ float wsm[4][8][68];
  __shared__ int   scs[4][64];
  int tid = threadIdx.x;
  int slot = tid >> 6;
  int node = blockIdx.x * 4 + slot;
  if (node >= N) return;
  int lane = tid & 63;
  int g = lane >> 3, q = lane & 7;
  int beg = offs[node], end = offs[node + 1];
  int deg = end - beg;
  float4 advlo = *(const float4*)&ad1[node * 8];
  float4 advhi = *(const float4*)&ad1[node * 8 + 4];
  float denom = 0.f;
  float4 acc0 = make_float4(0.f, 0.f, 0.f, 0.f);
  float4 acc1 = make_float4(0.f, 0.f, 0.f, 0.f);
  for (int c0 = 0; c0 < deg; c0 += 64) {
    int cn = min(64, deg - c0);
    // phase B: lane e<cn computes all 8 head weights for its edge
    if (lane < cn) {
      int sreg = csr[beg + c0 + lane];
      scs[slot][lane] = sreg;
      float4 alo = *(const float4*)&as1[sreg * 8];
      float4 ahi = *(const float4*)&as1[sreg * 8 + 4];
      wsm[slot][0][lane] = __expf(lrelu02(alo.x + advlo.x));
      wsm[slot][1][lane] = __expf(lrelu02(alo.y + advlo.y));
      wsm[slot][2][lane] = __expf(lrelu02(alo.z + advlo.z));
      wsm[slot][3][lane] = __expf(lrelu02(alo.w + advlo.w));
      wsm[slot][4][lane] = __expf(lrelu02(ahi.x + advhi.x));
      wsm[slot][5][lane] = __expf(lrelu02(ahi.y + advhi.y));
      wsm[slot][6][lane] = __expf(lrelu02(ahi.z + advhi.z));
      wsm[slot][7][lane] = __expf(lrelu02(ahi.w + advhi.w));
    }
    // phase C: group g takes edges i+g, i+8+g; lane loads its 8 channels
    int i = 0;
    for (; i + 16 <= cn; i += 16) {
      int e0 = i + g, e1 = i + 8 + g;
      int s0 = scs[slot][e0], s1 = scs[slot][e1];
      float w0 = wsm[slot][q][e0], w1 = wsm[slot][q][e1];
      uint4 p0 = *(const uint4*)&h1b[(unsigned)s0 * 64 + q * 8];
      uint4 p1 = *(const uint4*)&h1b[(unsigned)s1 * 64 + q * 8];
      denom += w0 + w1;
      acc0.x += w0 * lo16(p0.x); acc0.y += w0 * hi16(p0.x);
      acc0.z += w0 * lo16(p0.y); acc0.w += w0 * hi16(p0.y);
      acc1.x += w0 * lo16(p0.z); acc1.y += w0 * hi16(p0.z);
      acc1.z += w0 * lo16(p0.w); acc1.w += w0 * hi16(p0.w);
      acc0.x += w1 * lo16(p1.x); acc0.y += w1 * hi16(p1.x);
      acc0.z += w1 * lo16(p1.y); acc0.w += w1 * hi16(p1.y);
      acc1.x += w1 * lo16(p1.z); acc1.y += w1 * hi16(p1.z);
      acc1.z += w1 * lo16(p1.w); acc1.w += w1 * hi16(p1.w);
    }
    for (; i < cn; i += 8) {
      int e = i + g;
      if (e < cn) {
        int s = scs[slot][e];
        float w = wsm[slot][q][e];
        uint4 p = *(const uint4*)&h1b[(unsigned)s * 64 + q * 8];
        denom += w;
        acc0.x += w * lo16(p.x); acc0.y += w * hi16(p.x);
        acc0.z += w * lo16(p.y); acc0.w += w * hi16(p.y);
        acc1.x += w * lo16(p.z); acc1.y += w * hi16(p.z);
        acc1.z += w * lo16(p.w); acc1.w += w * hi16(p.w);
      }
    }
  }
  // combine the 8 edge-groups
#pragma unroll
  for (int off = 8; off <= 32; off <<= 1) {
    acc0.x += __shfl_xor(acc0.x, off); acc0.y += __shfl_xor(acc0.y, off);
    acc0.z += __shfl_xor(acc0.z, off); acc0.w += __shfl_xor(acc0.w, off);
    acc1.x += __shfl_xor(acc1.x, off); acc1.y += __shfl_xor(acc1.y, off);
    acc1.z += __shfl_xor(acc1.z, off); acc1.w += __shfl_xor(acc1.w, off);
    denom += __shfl_xor(denom, off);
  }
  float rd = 1.f / denom;
  float4 ba = *(const float4*)&b1[q * 8];
  float4 bb = *(const float4*)&b1[q * 8 + 4];
  float o[8];
  o[0] = acc0.x * rd + ba.x; o[1] = acc0.y * rd + ba.y;
  o[2] = acc0.z * rd + ba.z; o[3] = acc0.w * rd + ba.w;
  o[4] = acc1.x * rd + bb.x; o[5] = acc1.y * rd + bb.y;
  o[6] = acc1.z * rd + bb.z; o[7] = acc1.w * rd + bb.w;
#pragma unroll
  for (int j = 0; j < 8; ++j) o[j] = o[j] > 0.f ? o[j] : expm1f(o[j]);
  if (g == 0) {
    uint4 ob;
    ob.x = f2b(o[0]) | ((unsigned)f2b(o[1]) << 16);
    ob.y = f2b(o[2]) | ((unsigned)f2b(o[3]) << 16);
    ob.z = f2b(o[4]) | ((unsigned)f2b(o[5]) << 16);
    ob.w = f2b(o[6]) | ((unsigned)f2b(o[7]) << 16);
    *(uint4*)&helu_b[(size_t)node * 64 + q * 8] = ob;
  }
  // fused layer-2 alpha
  float4 wa0 = *(const float4*)&w2as[q * 8];
  float4 wa1 = *(const float4*)&w2as[q * 8 + 4];
  float4 wd0 = *(const float4*)&w2ad[q * 8];
  float4 wd1 = *(const float4*)&w2ad[q * 8 + 4];
  float s2 = o[0] * wa0.x + o[1] * wa0.y + o[2] * wa0.z + o[3] * wa0.w
           + o[4] * wa1.x + o[5] * wa1.y + o[6] * wa1.z + o[7] * wa1.w;
  float d2 = o[0] * wd0.x + o[1] * wd0.y + o[2] * wd0.z + o[3] * wd0.w
           + o[4] * wd1.x + o[5] * wd1.y + o[6] * wd1.z + o[7] * wd1.w;
#pragma unroll
  for (int off = 1; off <= 4; off <<= 1) {
    s2 += __shfl_xor(s2, off);
    d2 += __shfl_xor(d2, off);
  }
  if (lane == 0) { as2[node] = s2; ad2[node] = d2; }
}

// ---- Layer 2 aggregate (max-free, uint4 gather) over helu -----------------

__global__ __launch_bounds__(256) void k_agg2(const int* __restrict__ csr, const int* __restrict__ offs,
                                              const unsigned short* __restrict__ helu_b,
                                              const float* __restrict__ as2, const float* __restrict__ ad2,
                                              float* __restrict__ agg, int N) {
  __shared__ float wls[4][68];
  __shared__ int   scs[4][64];
  int tid = threadIdx.x;
  int slot = tid >> 6;
  int node = blockIdx.x * 4 + slot;
  if (node >= N) return;
  int lane = tid & 63;
  int g = lane >> 3, q = lane & 7;
  int beg = offs[node], end = offs[node + 1];
  int deg = end - beg;
  float adv = ad2[node];
  float denom = 0.f;
  float4 acc0 = make_float4(0.f, 0.f, 0.f, 0.f);
  float4 acc1 = make_float4(0.f, 0.f, 0.f, 0.f);
  for (int c0 = 0; c0 < deg; c0 += 64) {
    int cn = min(64, deg - c0);
    if (lane < cn) {
      int sreg = csr[beg + c0 + lane];
      scs[slot][lane] = sreg;
      wls[slot][lane] = __expf(lrelu02(as2[sreg] + adv));
    }
    int i = 0;
    for (; i + 16 <= cn; i += 16) {
      int e0 = i + g, e1 = i + 8 + g;
      int s0 = scs[slot][e0], s1 = scs[slot][e1];
      float w0 = wls[slot][e0], w1 = wls[slot][e1];
      uint4 p0 = *(const uint4*)&helu_b[(unsigned)s0 * 64 + q * 8];
      uint4 p1 = *(const uint4*)&helu_b[(unsigned)s1 * 64 + q * 8];
      denom += w0 + w1;
      acc0.x += w0 * lo16(p0.x); acc0.y += w0 * hi16(p0.x);
      acc0.z += w0 * lo16(p0.y); acc0.w += w0 * hi16(p0.y);
      acc1.x += w0 * lo16(p0.z); acc1.y += w0 * hi16(p0.z);
      acc1.z += w0 * lo16(p0.w); acc1.w += w0 * hi16(p0.w);
      acc0.x += w1 * lo16(p1.x); acc0.y += w1 * hi16(p1.x);
      acc0.z += w1 * lo16(p1.y); acc0.w += w1 * hi16(p1.y);
      acc1.x += w1 * lo16(p1.z); acc1.y += w1 * hi16(p1.z);
      acc1.z += w1 * lo16(p1.w); acc1.w += w1 * hi16(p1.w);
    }
    for (; i < cn; i += 8) {
      int e = i + g;
      if (e < cn) {
        int s = scs[slot][e];
        float w = wls[slot][e];
        uint4 p = *(const uint4*)&helu_b[(unsigned)s * 64 + q * 8];
        denom += w;
        acc0.x += w * lo16(p.x); acc0.y += w * hi16(p.x);
        acc0.z += w * lo16(p.y); acc0.w += w * hi16(p.y);
        acc1.x += w * lo16(p.z); acc1.y += w * hi16(p.z);
        acc1.z += w * lo16(p.w); acc1.w += w * hi16(p.w);
      }
    }
  }
#pragma unroll
  for (int off = 8; off <= 32; off <<= 1) {
    acc0.x += __shfl_xor(acc0.x, off); acc0.y += __shfl_xor(acc0.y, off);
    acc0.z += __shfl_xor(acc0.z, off); acc0.w += __shfl_xor(acc0.w, off);
    acc1.x += __shfl_xor(acc1.x, off); acc1.y += __shfl_xor(acc1.y, off);
    acc1.z += __shfl_xor(acc1.z, off); acc1.w += __shfl_xor(acc1.w, off);
    denom += __shfl_xor(denom, off);
  }
  if (g == 0) {
    float rd = 1.f / denom;
    float4 o0, o1;
    o0.x = acc0.x * rd; o0.y = acc0.y * rd; o0.z = acc0.z * rd; o0.w = acc0.w * rd;
    o1.x = acc1.x * rd; o1.y = acc1.y * rd; o1.z = acc1.z * rd; o1.w = acc1.w * rd;
    *(float4*)&agg[(size_t)node * 64 + q * 8] = o0;
    *(float4*)&agg[(size_t)node * 64 + q * 8 + 4] = o1;
  }
}

// ---- Final GEMM: out = sigmoid(agg @ W2 + b2)  [N,64]@[64,100] ------------

__global__ __launch_bounds__(256) void k_gemm2b(const float* __restrict__ agg, const float* __restrict__ W2,
                                                const float* __restrict__ b2, float* __restrict__ out, int N) {
  __shared__ float het[64][44];     // [k][row]
  __shared__ float w2l[64 * 100];   // [k][col]
  int tid = threadIdx.x;
  int row0 = blockIdx.x * 40;
  for (int i = tid; i < 6400; i += 256) w2l[i] = W2[i];
  for (int idx = tid; idx < 640; idx += 256) {
    int r = idx >> 4, kq = idx & 15;
    int grow = row0 + r;
    float4 v = make_float4(0.f, 0.f, 0.f, 0.f);
    if (grow < N) v = *(const float4*)&agg[(size_t)grow * 64 + kq * 4];
    het[kq * 4 + 0][r] = v.x; het[kq * 4 + 1][r] = v.y;
    het[kq * 4 + 2][r] = v.z; het[kq * 4 + 3][r] = v.w;
  }
  __syncthreads();
  int rg = tid / 25, cg = tid % 25;
  if (rg >= 10) return;
  float acc[4][4] = {};
#pragma unroll 4
  for (int k = 0; k < 64; ++k) {
    float4 xv = *(const float4*)&het[k][rg * 4];
    float4 wv = *(const float4*)&w2l[k * 100 + cg * 4];
    float xa[4] = {xv.x, xv.y, xv.z, xv.w};
    float wa[4] = {wv.x, wv.y, wv.z, wv.w};
#pragma unroll
    for (int i = 0; i < 4; ++i)
#pragma unroll
      for (int j = 0; j < 4; ++j) acc[i][j] += xa[i] * wa[j];
  }
  float bb[4];
#pragma unroll
  for (int j = 0; j < 4; ++j) bb[j] = b2[cg * 4 + j];
#pragma unroll
  for (int i = 0; i < 4; ++i) {
    int row = row0 + rg * 4 + i;
    if (row < N) {
      float4 o;
      o.x = 1.f / (1.f + __expf(-(acc[i][0] + bb[0])));
      o.y = 1.f / (1.f + __expf(-(acc[i][1] + bb[1])));
      o.z = 1.f / (1.f + __expf(-(acc[i][2] + bb[2])));
      o.w = 1.f / (1.f + __expf(-(acc[i][3] + bb[3])));
      *(float4*)&out[(size_t)row * 100 + cg * 4] = o;
    }
  }
}

// ---------------------------------------------------------------------------

extern "C" void kernel_launch(void* const* d_in, const int* in_sizes, int n_in,
                              void* d_out, int out_size, void* d_ws, size_t ws_size,
                              hipStream_t stream) {
  const float* x    = (const float*)d_in[0];
  const int*   ei   = (const int*)d_in[1];    // harness converts integer inputs to int32
  const float* W1   = (const float*)d_in[2];
  const float* a_s1 = (const float*)d_in[3];
  const float* a_d1 = (const float*)d_in[4];
  const float* b1   = (const float*)d_in[5];
  const float* W2   = (const float*)d_in[6];
  const float* a_s2 = (const float*)d_in[7];
  const float* a_d2 = (const float*)d_in[8];
  const float* b2   = (const float*)d_in[9];
  float* out = (float*)d_out;

  const int N = in_sizes[0] / 256;
  const int E = in_sizes[1] / 2;
  const int K = (N + BNN - 1) >> BSH;       // buckets (<=256 for N<=131072)

  char* w = (char*)d_ws;
  size_t off = 0;
  auto alloc = [&](size_t bytes) -> char* {
    char* p = w + off;
    off = (off + bytes + 255) & ~(size_t)255;
    return p;
  };
  unsigned short* h1b    = (unsigned short*)alloc((size_t)N * 64 * 2);
  unsigned short* helu_b = (unsigned short*)alloc((size_t)N * 64 * 2);
  unsigned short* w1t    = (unsigned short*)alloc(64 * 256 * 2);
  float* agg  = (float*)alloc((size_t)N * 64 * 4);
  float* as1  = (float*)alloc((size_t)N * 8 * 4);
  float* ad1  = (float*)alloc((size_t)N * 8 * 4);
  float* as2  = (float*)alloc((size_t)N * 4);
  float* ad2  = (float*)alloc((size_t)N * 4);
  float* w2as = (float*)alloc(64 * 4);
  float* w2ad = (float*)alloc(64 * 4);
  int*   offs   = (int*)alloc((size_t)(N + 1) * 4);
  int*   csr    = (int*)alloc((size_t)(E + N) * 4);
  int2*  binned = (int2*)alloc((size_t)E * 8);
  int*   bhist  = (int*)alloc((size_t)(K + 1) * 4);
  int*   bbase  = (int*)alloc((size_t)(K + 1) * 4);
  int*   bcur   = (int*)alloc((size_t)K * 4);
  (void)ws_size; (void)n_in; (void)out_size;

  hipMemsetAsync(bhist, 0, (size_t)K * 4, stream);

  int ebl = (E + 2047) / 2048;
  k_hist<<<ebl, 256, 0, stream>>>(ei, E, bhist);
  k_bscan<<<1, 256, 0, stream>>>(bhist, bbase, bcur, offs, K, E, N);
  k_bin<<<ebl, 256, 0, stream>>>(ei, E, bcur, binned);
  k_bucket<<<K, 256, 0, stream>>>(binned, bbase, offs, csr, N);

  k_prep<<<16, 256, 0, stream>>>(W1, w1t);
  k_proj<<<1, 128, 0, stream>>>(W2, a_s2, a_d2, w2as, w2ad);
  k_gemm1<<<(N + 63) / 64, 256, 0, stream>>>(x, w1t, a_s1, a_d1, h1b, as1, ad1, N);
  k_agg1<<<(N + 3) / 4, 256, 0, stream>>>(csr, offs, h1b, as1, ad1, b1, w2as, w2ad,
                                          helu_b, as2, ad2, N);
  k_agg2<<<(N + 3) / 4, 256, 0, stream>>>(csr, offs, helu_b, as2, ad2, agg, N);
  k_gemm2b<<<(N + 39) / 40, 256, 0, stream>>>(agg, W2, b2, out, N);
}

// Round 9
// 238.825 us; speedup vs baseline: 3.1046x; 1.1045x over previous
//
#include <hip/hip_runtime.h>
#include <hip/hip_bf16.h>
#include <cmath>

// ---------------------------------------------------------------------------
// GAT 2-layer forward.
// CSR build via 2-level bucketing. Layer1: bf16 MFMA GEMM (16x16x32) with
// fused alpha epilogue -> agg1 (max-free softmax, 8 nodes/wave, 8 lanes/node,
// uint4 row gather, per-lane-complete accumulators) fused with helu-bf16 +
// as2/ad2 projection. Layer2: same-structure aggregate (no LDS, shfl
// broadcasts), then fp32 GEMM W2 + bias + sigmoid.
// ---------------------------------------------------------------------------

#define BSH 9                 // 512 nodes per bucket; requires N <= 131072
#define BNN (1 << BSH)

typedef __attribute__((ext_vector_type(8))) short short8v;
typedef __attribute__((ext_vector_type(4))) float f32x4;

__device__ __forceinline__ float lrelu02(float v) { return v > 0.f ? v : 0.2f * v; }

__device__ __forceinline__ unsigned short f2b(float f) {
  union { float f; unsigned int i; } c; c.f = f;
  unsigned int r = c.i + 0x7FFFu + ((c.i >> 16) & 1u);   // RNE
  return (unsigned short)(r >> 16);
}
__device__ __forceinline__ float lo16(unsigned int u) {
  union { float f; unsigned int i; } c; c.i = u << 16; return c.f;
}
__device__ __forceinline__ float hi16(unsigned int u) {
  union { float f; unsigned int i; } c; c.i = u & 0xFFFF0000u; return c.f;
}

// ---- CSR build: pass A1 — bucket histogram --------------------------------

__global__ __launch_bounds__(256) void k_hist(const int* __restrict__ ei, int E,
                                              int* __restrict__ bhist) {
  __shared__ int lh[256];
  int tid = threadIdx.x;
  lh[tid] = 0;
  __syncthreads();
  int base = blockIdx.x * 2048;
#pragma unroll
  for (int j = 0; j < 8; ++j) {
    int e = base + j * 256 + tid;
    if (e < E) atomicAdd(&lh[ei[E + e] >> BSH], 1);
  }
  __syncthreads();
  if (lh[tid]) atomicAdd(&bhist[tid], lh[tid]);
}

// ---- pass A2 — scan bucket counts (single block) --------------------------

__global__ __launch_bounds__(256) void k_bscan(const int* __restrict__ bhist,
                                               int* __restrict__ bbase, int* __restrict__ bcur,
                                               int* __restrict__ offs, int K, int E, int N) {
  __shared__ int s[256];
  int tid = threadIdx.x;
  int v = (tid < K) ? bhist[tid] : 0;
  s[tid] = v;
  __syncthreads();
  for (int off = 1; off < 256; off <<= 1) {
    int t = (tid >= off) ? s[tid - off] : 0;
    __syncthreads();
    s[tid] += t;
    __syncthreads();
  }
  int excl = s[tid] - v;
  if (tid < K) { bbase[tid] = excl; bcur[tid] = excl; }
  if (tid == 255) bbase[K] = s[255];    // = E
  if (tid == 0) offs[N] = E + N;
}

// ---- pass A3 — bin edges into buckets as (src, dst_local) -----------------

__global__ __launch_bounds__(256) void k_bin(const int* __restrict__ ei, int E,
                                             int* __restrict__ bcur, int2* __restrict__ binned) {
  __shared__ int lh[256];
  __shared__ int lbase[256];
  int tid = threadIdx.x;
  lh[tid] = 0;
  __syncthreads();
  int base = blockIdx.x * 2048;
  int bj[8], rk[8], sj[8], dl[8];
#pragma unroll
  for (int j = 0; j < 8; ++j) {
    int e = base + j * 256 + tid;
    bj[j] = -1;
    if (e < E) {
      sj[j] = ei[e];
      int d = ei[E + e];
      bj[j] = d >> BSH;
      dl[j] = d & (BNN - 1);
      rk[j] = atomicAdd(&lh[bj[j]], 1);
    }
  }
  __syncthreads();
  if (lh[tid]) lbase[tid] = atomicAdd(&bcur[tid], lh[tid]);
  __syncthreads();
#pragma unroll
  for (int j = 0; j < 8; ++j)
    if (bj[j] >= 0) binned[lbase[bj[j]] + rk[j]] = make_int2(sj[j], dl[j]);
}

// ---- pass B — per-bucket CSR fill (one block per bucket) ------------------

__global__ __launch_bounds__(256) void k_bucket(const int2* __restrict__ binned,
                                                const int* __restrict__ bbase,
                                                int* __restrict__ offs, int* __restrict__ csr,
                                                int N) {
  __shared__ int hist[BNN], loffS[BNN], cur[BNN];
  __shared__ int s[256];
  int tid = threadIdx.x;
  int b = blockIdx.x;
  int node0 = b << BSH;
  int sl = min(BNN, N - node0);
  int e0 = bbase[b], e1 = bbase[b + 1];
  int cbase = e0 + min(node0, N);          // csr base incl. upstream self-loops
  hist[tid] = 0; hist[tid + 256] = 0;
  __syncthreads();
  for (int e = e0 + tid; e < e1; e += 256) atomicAdd(&hist[binned[e].y], 1);
  __syncthreads();
  int a0 = hist[2 * tid], a1 = hist[2 * tid + 1];
  s[tid] = a0 + a1;
  __syncthreads();
  for (int off = 1; off < 256; off <<= 1) {
    int t = (tid >= off) ? s[tid - off] : 0;
    __syncthreads();
    s[tid] += t;
    __syncthreads();
  }
  int excl = s[tid] - (a0 + a1);
  loffS[2 * tid]     = excl + 2 * tid;
  loffS[2 * tid + 1] = excl + a0 + 2 * tid + 1;
  __syncthreads();
  cur[2 * tid] = loffS[2 * tid];
  cur[2 * tid + 1] = loffS[2 * tid + 1];
  if (2 * tid < sl)     offs[node0 + 2 * tid]     = cbase + loffS[2 * tid];
  if (2 * tid + 1 < sl) offs[node0 + 2 * tid + 1] = cbase + loffS[2 * tid + 1];
  __syncthreads();
  for (int e = e0 + tid; e < e1; e += 256) {
    int2 u = binned[e];
    int p = atomicAdd(&cur[u.y], 1);
    csr[cbase + p] = u.x;
  }
  for (int i = tid; i < sl; i += 256) {
    int p = atomicAdd(&cur[i], 1);
    csr[cbase + p] = node0 + i;            // self loop
  }
}

// ---- prep: W1 transposed to bf16 [64 cols][256 k] -------------------------

__global__ __launch_bounds__(256) void k_prep(const float* __restrict__ W1,
                                              unsigned short* __restrict__ w1t) {
  int idx = blockIdx.x * 256 + threadIdx.x;   // 0..4095
#pragma unroll
  for (int j = 0; j < 4; ++j) {
    int e = idx * 4 + j;                      // flat w1t index = col*256 + k
    int col = e >> 8, k = e & 255;
    w1t[e] = f2b(W1[k * 64 + col]);
  }
}

// ---- projection of layer-2 attention vectors through W2 -------------------

__global__ __launch_bounds__(128) void k_proj(const float* __restrict__ W2,
                                              const float* __restrict__ a2s,
                                              const float* __restrict__ a2d,
                                              float* __restrict__ w2as, float* __restrict__ w2ad) {
  int t = threadIdx.x;
  if (t < 64) {
    float s = 0.f;
    for (int k = 0; k < 100; ++k) s += W2[t * 100 + k] * a2s[k];
    w2as[t] = s;
  } else {
    int c = t - 64;
    float s = 0.f;
    for (int k = 0; k < 100; ++k) s += W2[c * 100 + k] * a2d[k];
    w2ad[c] = s;
  }
}

// ---- Layer 1 GEMM via MFMA: h1 = x @ W1 (bf16 in/out, fp32 acc) -----------

__global__ __launch_bounds__(256) void k_gemm1(const float* __restrict__ x,
                                               const unsigned short* __restrict__ w1t,
                                               const float* __restrict__ av_s, const float* __restrict__ av_d,
                                               unsigned short* __restrict__ h1b, float* __restrict__ as1,
                                               float* __restrict__ ad1, int N) {
  __shared__ unsigned short xs[64 * 264];
  __shared__ unsigned short ws[64 * 264];
  int tid = threadIdx.x;
  int row0 = blockIdx.x * 64;
#pragma unroll
  for (int it = 0; it < 8; ++it) {
    int slot = tid + it * 256;              // 0..2047
    int row = slot >> 5, kg = slot & 31;    // k-base = kg*8
    int grow = row0 + row;
    uint4 pk = make_uint4(0u, 0u, 0u, 0u);
    if (grow < N) {
      const float* px = &x[(size_t)grow * 256 + kg * 8];
      float4 v0 = *(const float4*)px;
      float4 v1 = *(const float4*)(px + 4);
      pk.x = f2b(v0.x) | ((unsigned)f2b(v0.y) << 16);
      pk.y = f2b(v0.z) | ((unsigned)f2b(v0.w) << 16);
      pk.z = f2b(v1.x) | ((unsigned)f2b(v1.y) << 16);
      pk.w = f2b(v1.z) | ((unsigned)f2b(v1.w) << 16);
    }
    *(uint4*)&xs[row * 264 + kg * 8] = pk;
    *(uint4*)&ws[row * 264 + kg * 8] = *(const uint4*)&w1t[row * 256 + kg * 8];
  }
  __syncthreads();
  int w = tid >> 6, lane = tid & 63;
  int r16 = lane & 15, kg4 = lane >> 4;
  f32x4 acc[4];
#pragma unroll
  for (int f = 0; f < 4; ++f) acc[f] = (f32x4){0.f, 0.f, 0.f, 0.f};
  const unsigned short* xrow = &xs[(16 * w + r16) * 264 + kg4 * 8];
#pragma unroll
  for (int ks = 0; ks < 8; ++ks) {
    short8v a = *(const short8v*)(xrow + ks * 32);
#pragma unroll
    for (int f = 0; f < 4; ++f) {
      short8v b = *(const short8v*)&ws[(16 * f + r16) * 264 + kg4 * 8 + ks * 32];
      acc[f] = __builtin_amdgcn_mfma_f32_16x16x32_bf16(a, b, acc[f], 0, 0, 0);
    }
  }
  float avv[4], bvv[4];
#pragma unroll
  for (int f = 0; f < 4; ++f) { avv[f] = av_s[16 * f + r16]; bvv[f] = av_d[16 * f + r16]; }
  int rbase = row0 + 16 * w + kg4 * 4;
#pragma unroll
  for (int reg = 0; reg < 4; ++reg) {
    int row = rbase + reg;
    bool ok = row < N;
    if (ok) {
#pragma unroll
      for (int f = 0; f < 4; ++f)
        h1b[(size_t)row * 64 + 16 * f + r16] = f2b(acc[f][reg]);
    }
    float ts[4], td[4];
#pragma unroll
    for (int f = 0; f < 4; ++f) { ts[f] = acc[f][reg] * avv[f]; td[f] = acc[f][reg] * bvv[f]; }
#pragma unroll
    for (int off = 1; off <= 4; off <<= 1) {
#pragma unroll
      for (int f = 0; f < 4; ++f) {
        ts[f] += __shfl_xor(ts[f], off);
        td[f] += __shfl_xor(td[f], off);
      }
    }
    if (ok && (r16 & 7) == 0) {
      int bsel = r16 >> 3;
#pragma unroll
      for (int f = 0; f < 4; ++f) {
        as1[row * 8 + 2 * f + bsel] = ts[f];
        ad1[row * 8 + 2 * f + bsel] = td[f];
      }
    }
  }
}

// ---- Layer 1 aggregate: 8 nodes/wave, 8 lanes/node ------------------------
// lane: sub=lane>>3 (node), q=lane&7 (head q = channels 8q..8q+7).
// Chunk of 8 edges/node: lane q computes all 8 head-weights of edge q ->
// wsm[sub][h][q] (pad 9 -> <=2-way banks). Gather loop: every lane walks ALL
// its node's edges (src via shfl, weight via wsm) so denom/acc are complete
// per-lane -- no reductions. Epilogue serves 8 nodes per pass.

__global__ __launch_bounds__(256) void k_agg1(const int* __restrict__ csr, const int* __restrict__ offs,
                                              const unsigned short* __restrict__ h1b,
                                              const float* __restrict__ as1, const float* __restrict__ ad1,
                                              const float* __restrict__ b1,
                                              const float* __restrict__ w2as, const float* __restrict__ w2ad,
                                              unsigned short* __restrict__ helu_b,
                                              float* __restrict__ as2, float* __restrict__ ad2, int N) {
  __shared__ float wsm[4][8][8][9];   // [wave][sub][head][edge(pad 9)]
  int tid = threadIdx.x;
  int w = tid >> 6, lane = tid & 63;
  int sub = lane >> 3, q = lane & 7;
  int base = sub << 3;                // first lane of this sub-group
  int node = blockIdx.x * 32 + w * 8 + sub;
  bool valid = node < N;
  int beg = 0, end = 0;
  if (valid) { beg = offs[node]; end = offs[node + 1]; }
  int deg = end - beg;
  int dm = deg;
  dm = max(dm, __shfl_xor(dm, 8));
  dm = max(dm, __shfl_xor(dm, 16));
  dm = max(dm, __shfl_xor(dm, 32));
  float4 advlo = make_float4(0.f, 0.f, 0.f, 0.f), advhi = advlo;
  if (valid) {
    advlo = *(const float4*)&ad1[node * 8];
    advhi = *(const float4*)&ad1[node * 8 + 4];
  }
  float denom = 0.f;
  float4 acc0 = make_float4(0.f, 0.f, 0.f, 0.f);
  float4 acc1 = make_float4(0.f, 0.f, 0.f, 0.f);
  for (int c0 = 0; c0 < dm; c0 += 8) {
    int cn = min(8, deg - c0);          // may be <= 0 for finished nodes
    int sreg = 0;
    if (q < cn) {
      sreg = csr[beg + c0 + q];
      float4 alo = *(const float4*)&as1[sreg * 8];
      float4 ahi = *(const float4*)&as1[sreg * 8 + 4];
      wsm[w][sub][0][q] = __expf(lrelu02(alo.x + advlo.x));
      wsm[w][sub][1][q] = __expf(lrelu02(alo.y + advlo.y));
      wsm[w][sub][2][q] = __expf(lrelu02(alo.z + advlo.z));
      wsm[w][sub][3][q] = __expf(lrelu02(alo.w + advlo.w));
      wsm[w][sub][4][q] = __expf(lrelu02(ahi.x + advhi.x));
      wsm[w][sub][5][q] = __expf(lrelu02(ahi.y + advhi.y));
      wsm[w][sub][6][q] = __expf(lrelu02(ahi.z + advhi.z));
      wsm[w][sub][7][q] = __expf(lrelu02(ahi.w + advhi.w));
    }
    int i = 0;
    for (; i + 2 <= cn; i += 2) {
      int s0 = __shfl(sreg, base + i);
      int s1 = __shfl(sreg, base + i + 1);
      float w0 = wsm[w][sub][q][i];
      float w1 = wsm[w][sub][q][i + 1];
      uint4 p0 = *(const uint4*)&h1b[(unsigned)s0 * 64 + q * 8];
      uint4 p1 = *(const uint4*)&h1b[(unsigned)s1 * 64 + q * 8];
      denom += w0 + w1;
      acc0.x += w0 * lo16(p0.x); acc0.y += w0 * hi16(p0.x);
      acc0.z += w0 * lo16(p0.y); acc0.w += w0 * hi16(p0.y);
      acc1.x += w0 * lo16(p0.z); acc1.y += w0 * hi16(p0.z);
      acc1.z += w0 * lo16(p0.w); acc1.w += w0 * hi16(p0.w);
      acc0.x += w1 * lo16(p1.x); acc0.y += w1 * hi16(p1.x);
      acc0.z += w1 * lo16(p1.y); acc0.w += w1 * hi16(p1.y);
      acc1.x += w1 * lo16(p1.z); acc1.y += w1 * hi16(p1.z);
      acc1.z += w1 * lo16(p1.w); acc1.w += w1 * hi16(p1.w);
    }
    if (i < cn) {
      int s0 = __shfl(sreg, base + i);
      float w0 = wsm[w][sub][q][i];
      uint4 p0 = *(const uint4*)&h1b[(unsigned)s0 * 64 + q * 8];
      denom += w0;
      acc0.x += w0 * lo16(p0.x); acc0.y += w0 * hi16(p0.x);
      acc0.z += w0 * lo16(p0.y); acc0.w += w0 * hi16(p0.y);
      acc1.x += w0 * lo16(p0.z); acc1.y += w0 * hi16(p0.z);
      acc1.z += w0 * lo16(p0.w); acc1.w += w0 * hi16(p0.w);
    }
  }
  // epilogue (denom/acc already complete per lane)
  float rd = 1.f / denom;
  float4 ba = valid ? *(const float4*)&b1[q * 8] : make_float4(0.f, 0.f, 0.f, 0.f);
  float4 bb = valid ? *(const float4*)&b1[q * 8 + 4] : make_float4(0.f, 0.f, 0.f, 0.f);
  float o[8];
  o[0] = acc0.x * rd + ba.x; o[1] = acc0.y * rd + ba.y;
  o[2] = acc0.z * rd + ba.z; o[3] = acc0.w * rd + ba.w;
  o[4] = acc1.x * rd + bb.x; o[5] = acc1.y * rd + bb.y;
  o[6] = acc1.z * rd + bb.z; o[7] = acc1.w * rd + bb.w;
#pragma unroll
  for (int j = 0; j < 8; ++j) o[j] = o[j] > 0.f ? o[j] : __expf(o[j]) - 1.f;  // ELU
  if (valid) {
    uint4 ob;
    ob.x = f2b(o[0]) | ((unsigned)f2b(o[1]) << 16);
    ob.y = f2b(o[2]) | ((unsigned)f2b(o[3]) << 16);
    ob.z = f2b(o[4]) | ((unsigned)f2b(o[5]) << 16);
    ob.w = f2b(o[6]) | ((unsigned)f2b(o[7]) << 16);
    *(uint4*)&helu_b[(size_t)node * 64 + q * 8] = ob;
  }
  // fused layer-2 alpha projection (reduce over the 8 lanes of the node)
  float s2 = 0.f, d2 = 0.f;
  if (valid) {
    float4 wa0 = *(const float4*)&w2as[q * 8];
    float4 wa1 = *(const float4*)&w2as[q * 8 + 4];
    float4 wd0 = *(const float4*)&w2ad[q * 8];
    float4 wd1 = *(const float4*)&w2ad[q * 8 + 4];
    s2 = o[0] * wa0.x + o[1] * wa0.y + o[2] * wa0.z + o[3] * wa0.w
       + o[4] * wa1.x + o[5] * wa1.y + o[6] * wa1.z + o[7] * wa1.w;
    d2 = o[0] * wd0.x + o[1] * wd0.y + o[2] * wd0.z + o[3] * wd0.w
       + o[4] * wd1.x + o[5] * wd1.y + o[6] * wd1.z + o[7] * wd1.w;
  }
#pragma unroll
  for (int off = 1; off <= 4; off <<= 1) {
    s2 += __shfl_xor(s2, off);
    d2 += __shfl_xor(d2, off);
  }
  if (valid && q == 0) { as2[node] = s2; ad2[node] = d2; }
}

// ---- Layer 2 aggregate: 8 nodes/wave, 8 lanes/node, no LDS ----------------

__global__ __launch_bounds__(256) void k_agg2(const int* __restrict__ csr, const int* __restrict__ offs,
                                              const unsigned short* __restrict__ helu_b,
                                              const float* __restrict__ as2, const float* __restrict__ ad2,
                                              float* __restrict__ agg, int N) {
  int tid = threadIdx.x;
  int lane = tid & 63;
  int sub = lane >> 3, q = lane & 7;
  int base = sub << 3;
  int node = blockIdx.x * 32 + (tid >> 6) * 8 + sub;
  bool valid = node < N;
  int beg = 0, end = 0;
  if (valid) { beg = offs[node]; end = offs[node + 1]; }
  int deg = end - beg;
  int dm = deg;
  dm = max(dm, __shfl_xor(dm, 8));
  dm = max(dm, __shfl_xor(dm, 16));
  dm = max(dm, __shfl_xor(dm, 32));
  float adv = valid ? ad2[node] : 0.f;
  float denom = 0.f;
  float4 acc0 = make_float4(0.f, 0.f, 0.f, 0.f);
  float4 acc1 = make_float4(0.f, 0.f, 0.f, 0.f);
  for (int c0 = 0; c0 < dm; c0 += 8) {
    int cn = min(8, deg - c0);
    int sreg = 0; float wq = 0.f;
    if (q < cn) {
      sreg = csr[beg + c0 + q];
      wq = __expf(lrelu02(as2[sreg] + adv));
    }
    int i = 0;
    for (; i + 2 <= cn; i += 2) {
      int s0 = __shfl(sreg, base + i);
      int s1 = __shfl(sreg, base + i + 1);
      float w0 = __shfl(wq, base + i);
      float w1 = __shfl(wq, base + i + 1);
      uint4 p0 = *(const uint4*)&helu_b[(unsigned)s0 * 64 + q * 8];
      uint4 p1 = *(const uint4*)&helu_b[(unsigned)s1 * 64 + q * 8];
      denom += w0 + w1;
      acc0.x += w0 * lo16(p0.x); acc0.y += w0 * hi16(p0.x);
      acc0.z += w0 * lo16(p0.y); acc0.w += w0 * hi16(p0.y);
      acc1.x += w0 * lo16(p0.z); acc1.y += w0 * hi16(p0.z);
      acc1.z += w0 * lo16(p0.w); acc1.w += w0 * hi16(p0.w);
      acc0.x += w1 * lo16(p1.x); acc0.y += w1 * hi16(p1.x);
      acc0.z += w1 * lo16(p1.y); acc0.w += w1 * hi16(p1.y);
      acc1.x += w1 * lo16(p1.z); acc1.y += w1 * hi16(p1.z);
      acc1.z += w1 * lo16(p1.w); acc1.w += w1 * hi16(p1.w);
    }
    if (i < cn) {
      int s0 = __shfl(sreg, base + i);
      float w0 = __shfl(wq, base + i);
      uint4 p0 = *(const uint4*)&helu_b[(unsigned)s0 * 64 + q * 8];
      denom += w0;
      acc0.x += w0 * lo16(p0.x); acc0.y += w0 * hi16(p0.x);
      acc0.z += w0 * lo16(p0.y); acc0.w += w0 * hi16(p0.y);
      acc1.x += w0 * lo16(p0.z); acc1.y += w0 * hi16(p0.z);
      acc1.z += w0 * lo16(p0.w); acc1.w += w0 * hi16(p0.w);
    }
  }
  if (valid) {
    float rd = 1.f / denom;
    float4 o0, o1;
    o0.x = acc0.x * rd; o0.y = acc0.y * rd; o0.z = acc0.z * rd; o0.w = acc0.w * rd;
    o1.x = acc1.x * rd; o1.y = acc1.y * rd; o1.z = acc1.z * rd; o1.w = acc1.w * rd;
    *(float4*)&agg[(size_t)node * 64 + q * 8] = o0;
    *(float4*)&agg[(size_t)node * 64 + q * 8 + 4] = o1;
  }
}

// ---- Final GEMM: out = sigmoid(agg @ W2 + b2)  [N,64]@[64,100] ------------

__global__ __launch_bounds__(256) void k_gemm2b(const float* __restrict__ agg, const float* __restrict__ W2,
                                                const float* __restrict__ b2, float* __restrict__ out, int N) {
  __shared__ float het[64][44];     // [k][row]
  __shared__ float w2l[64 * 100];   // [k][col]
  int tid = threadIdx.x;
  int row0 = blockIdx.x * 40;
  for (int i = tid; i < 6400; i += 256) w2l[i] = W2[i];
  for (int idx = tid; idx < 640; idx += 256) {
    int r = idx >> 4, kq = idx & 15;
    int grow = row0 + r;
    float4 v = make_float4(0.f, 0.f, 0.f, 0.f);
    if (grow < N) v = *(const float4*)&agg[(size_t)grow * 64 + kq * 4];
    het[kq * 4 + 0][r] = v.x; het[kq * 4 + 1][r] = v.y;
    het[kq * 4 + 2][r] = v.z; het[kq * 4 + 3][r] = v.w;
  }
  __syncthreads();
  int rg = tid / 25, cg = tid % 25;
  if (rg >= 10) return;
  float acc[4][4] = {};
#pragma unroll 4
  for (int k = 0; k < 64; ++k) {
    float4 xv = *(const float4*)&het[k][rg * 4];
    float4 wv = *(const float4*)&w2l[k * 100 + cg * 4];
    float xa[4] = {xv.x, xv.y, xv.z, xv.w};
    float wa[4] = {wv.x, wv.y, wv.z, wv.w};
#pragma unroll
    for (int i = 0; i < 4; ++i)
#pragma unroll
      for (int j = 0; j < 4; ++j) acc[i][j] += xa[i] * wa[j];
  }
  float bb[4];
#pragma unroll
  for (int j = 0; j < 4; ++j) bb[j] = b2[cg * 4 + j];
#pragma unroll
  for (int i = 0; i < 4; ++i) {
    int row = row0 + rg * 4 + i;
    if (row < N) {
      float4 o;
      o.x = 1.f / (1.f + __expf(-(acc[i][0] + bb[0])));
      o.y = 1.f / (1.f + __expf(-(acc[i][1] + bb[1])));
      o.z = 1.f / (1.f + __expf(-(acc[i][2] + bb[2])));
      o.w = 1.f / (1.f + __expf(-(acc[i][3] + bb[3])));
      *(float4*)&out[(size_t)row * 100 + cg * 4] = o;
    }
  }
}

// ---------------------------------------------------------------------------

extern "C" void kernel_launch(void* const* d_in, const int* in_sizes, int n_in,
                              void* d_out, int out_size, void* d_ws, size_t ws_size,
                              hipStream_t stream) {
  const float* x    = (const float*)d_in[0];
  const int*   ei   = (const int*)d_in[1];    // harness converts integer inputs to int32
  const float* W1   = (const float*)d_in[2];
  const float* a_s1 = (const float*)d_in[3];
  const float* a_d1 = (const float*)d_in[4];
  const float* b1   = (const float*)d_in[5];
  const float* W2   = (const float*)d_in[6];
  const float* a_s2 = (const float*)d_in[7];
  const float* a_d2 = (const float*)d_in[8];
  const float* b2   = (const float*)d_in[9];
  float* out = (float*)d_out;

  const int N = in_sizes[0] / 256;
  const int E = in_sizes[1] / 2;
  const int K = (N + BNN - 1) >> BSH;       // buckets (<=256 for N<=131072)

  char* w = (char*)d_ws;
  size_t off = 0;
  auto alloc = [&](size_t bytes) -> char* {
    char* p = w + off;
    off = (off + bytes + 255) & ~(size_t)255;
    return p;
  };
  unsigned short* h1b    = (unsigned short*)alloc((size_t)N * 64 * 2);
  unsigned short* helu_b = (unsigned short*)alloc((size_t)N * 64 * 2);
  unsigned short* w1t    = (unsigned short*)alloc(64 * 256 * 2);
  float* agg  = (float*)alloc((size_t)N * 64 * 4);
  float* as1  = (float*)alloc((size_t)N * 8 * 4);
  float* ad1  = (float*)alloc((size_t)N * 8 * 4);
  float* as2  = (float*)alloc((size_t)N * 4);
  float* ad2  = (float*)alloc((size_t)N * 4);
  float* w2as = (float*)alloc(64 * 4);
  float* w2ad = (float*)alloc(64 * 4);
  int*   offs   = (int*)alloc((size_t)(N + 1) * 4);
  int*   csr    = (int*)alloc((size_t)(E + N) * 4);
  int2*  binned = (int2*)alloc((size_t)E * 8);
  int*   bhist  = (int*)alloc((size_t)(K + 1) * 4);
  int*   bbase  = (int*)alloc((size_t)(K + 1) * 4);
  int*   bcur   = (int*)alloc((size_t)K * 4);
  (void)ws_size; (void)n_in; (void)out_size;

  hipMemsetAsync(bhist, 0, (size_t)K * 4, stream);

  int ebl = (E + 2047) / 2048;
  k_hist<<<ebl, 256, 0, stream>>>(ei, E, bhist);
  k_bscan<<<1, 256, 0, stream>>>(bhist, bbase, bcur, offs, K, E, N);
  k_bin<<<ebl, 256, 0, stream>>>(ei, E, bcur, binned);
  k_bucket<<<K, 256, 0, stream>>>(binned, bbase, offs, csr, N);

  k_prep<<<16, 256, 0, stream>>>(W1, w1t);
  k_proj<<<1, 128, 0, stream>>>(W2, a_s2, a_d2, w2as, w2ad);
  k_gemm1<<<(N + 63) / 64, 256, 0, stream>>>(x, w1t, a_s1, a_d1, h1b, as1, ad1, N);
  k_agg1<<<(N + 31) / 32, 256, 0, stream>>>(csr, offs, h1b, as1, ad1, b1, w2as, w2ad,
                                            helu_b, as2, ad2, N);
  k_agg2<<<(N + 31) / 32, 256, 0, stream>>>(csr, offs, helu_b, as2, ad2, agg, N);
  k_gemm2b<<<(N + 39) / 40, 256, 0, stream>>>(agg, W2, b2, out, N);
}